// Round 2
// baseline (1577.177 us; speedup 1.0000x reference)
//
#include <hip/hip_runtime.h>
#include <cstdint>
#include <cstddef>

// Problem constants
#define B_     4
#define NPATCH 1024
#define LSEQ   1025
#define PDIM   768
#define DIM    512
#define OUTD   512
#define DIN    1024
#define DSTATE 16
#define DTRANK 32
#define KCONV  4
#define NBLK   2
#define MROWS  (B_*LSEQ)   // 4100

__device__ __forceinline__ float sigmoidf_(float x){ return 1.f/(1.f+__expf(-x)); }
__device__ __forceinline__ float geluf_(float x){ return 0.5f*x*(1.f+erff(x*0.70710678118654752f)); }

// ---------------- generic f32 tiled GEMM: C[M,N] = A[M,K(lda)] @ W[K,N(ldw)] ----------------
// act: 0 = none, 1 = softplus
#define BM 64
#define BN 64
#define BK 16

__global__ __launch_bounds__(256) void gemm_f32(
    const float* __restrict__ A, int lda,
    const float* __restrict__ W, int ldw,
    float* __restrict__ C, int ldc,
    int M, int N, int K,
    const float* __restrict__ bias,
    const float* __restrict__ addsrc,   // if non-null: C += addsrc[r*ldc + c] (residual)
    int act)
{
    __shared__ float As[BK][BM+4];
    __shared__ float Bs[BK][BN+4];
    int tid = threadIdx.x;
    int tx = tid & 15, ty = tid >> 4;
    int m0 = blockIdx.y * BM, n0 = blockIdx.x * BN;
    float acc[4][4] = {};

    for (int k0 = 0; k0 < K; k0 += BK) {
        // A tile: 64 rows x 16 k ; each thread one float4 along k
        {
            int r  = tid >> 2;
            int kq = (tid & 3) << 2;
            float4 va = make_float4(0.f,0.f,0.f,0.f);
            int gr = m0 + r;
            if (gr < M) va = *reinterpret_cast<const float4*>(A + (size_t)gr*lda + k0 + kq);
            As[kq+0][r]=va.x; As[kq+1][r]=va.y; As[kq+2][r]=va.z; As[kq+3][r]=va.w;
        }
        // W tile: 16 k x 64 n ; each thread one float4 along n (K,N always multiples of 16/64)
        {
            int kk = tid >> 4;
            int nq = (tid & 15) << 2;
            float4 vb = *reinterpret_cast<const float4*>(W + (size_t)(k0+kk)*ldw + n0 + nq);
            Bs[kk][nq+0]=vb.x; Bs[kk][nq+1]=vb.y; Bs[kk][nq+2]=vb.z; Bs[kk][nq+3]=vb.w;
        }
        __syncthreads();
        #pragma unroll
        for (int k = 0; k < BK; ++k) {
            float a0=As[k][ty*4+0],a1=As[k][ty*4+1],a2=As[k][ty*4+2],a3=As[k][ty*4+3];
            float b0=Bs[k][tx*4+0],b1=Bs[k][tx*4+1],b2=Bs[k][tx*4+2],b3=Bs[k][tx*4+3];
            acc[0][0]=fmaf(a0,b0,acc[0][0]); acc[0][1]=fmaf(a0,b1,acc[0][1]);
            acc[0][2]=fmaf(a0,b2,acc[0][2]); acc[0][3]=fmaf(a0,b3,acc[0][3]);
            acc[1][0]=fmaf(a1,b0,acc[1][0]); acc[1][1]=fmaf(a1,b1,acc[1][1]);
            acc[1][2]=fmaf(a1,b2,acc[1][2]); acc[1][3]=fmaf(a1,b3,acc[1][3]);
            acc[2][0]=fmaf(a2,b0,acc[2][0]); acc[2][1]=fmaf(a2,b1,acc[2][1]);
            acc[2][2]=fmaf(a2,b2,acc[2][2]); acc[2][3]=fmaf(a2,b3,acc[2][3]);
            acc[3][0]=fmaf(a3,b0,acc[3][0]); acc[3][1]=fmaf(a3,b1,acc[3][1]);
            acc[3][2]=fmaf(a3,b2,acc[3][2]); acc[3][3]=fmaf(a3,b3,acc[3][3]);
        }
        __syncthreads();
    }
    #pragma unroll
    for (int i = 0; i < 4; ++i) {
        int r = m0 + ty*4 + i;
        if (r >= M) continue;
        #pragma unroll
        for (int j = 0; j < 4; ++j) {
            int c = n0 + tx*4 + j;
            float v = acc[i][j];
            if (bias)   v += bias[c];
            if (addsrc) v += addsrc[(size_t)r*ldc + c];
            if (act == 1) v = (v > 20.f) ? v : log1pf(__expf(v));
            C[(size_t)r*ldc + c] = v;
        }
    }
}

// ---------------- assemble x = concat(cls, patches) + pos ----------------
__global__ __launch_bounds__(256) void assemble_x(
    const float* __restrict__ tmp,   // [4096, 512] patch GEMM output (bias already added)
    const float* __restrict__ cls,   // [512]
    const float* __restrict__ pos,   // [1025, 512]
    float* __restrict__ x)           // [4100, 512]
{
    int idx = blockIdx.x*256 + threadIdx.x;   // 4*1025*512 total
    int d = idx & 511;
    int r = idx >> 9;
    int l = r % LSEQ;
    int b = r / LSEQ;
    float v = (l == 0) ? cls[d] : tmp[((size_t)(b*NPATCH + l-1))*DIM + d];
    x[idx] = v + pos[(size_t)l*DIM + d];
}

// ---------------- row LayerNorm (+optional exact GELU), ncols = 512 ----------------
// act: 0 = none, 2 = gelu
__global__ __launch_bounds__(256) void ln_act(
    const float* __restrict__ in, const float* __restrict__ gw, const float* __restrict__ gb,
    float* __restrict__ out, int act)
{
    int row = blockIdx.x;
    const float* p = in + (size_t)row * 512;
    int t = threadIdx.x;
    float v0 = p[t], v1 = p[t + 256];
    float s = v0 + v1, q = v0*v0 + v1*v1;
    #pragma unroll
    for (int o = 32; o; o >>= 1) { s += __shfl_xor(s, o); q += __shfl_xor(q, o); }
    __shared__ float ls[4], lq[4];
    int w = t >> 6;
    if ((t & 63) == 0) { ls[w] = s; lq[w] = q; }
    __syncthreads();
    s = ls[0]+ls[1]+ls[2]+ls[3];
    q = lq[0]+lq[1]+lq[2]+lq[3];
    float mean = s * (1.f/512.f);
    float var  = q * (1.f/512.f) - mean*mean;
    float inv  = rsqrtf(var + 1e-5f);
    float o0 = (v0-mean)*inv*gw[t]     + gb[t];
    float o1 = (v1-mean)*inv*gw[t+256] + gb[t+256];
    if (act == 2) { o0 = geluf_(o0); o1 = geluf_(o1); }
    out[(size_t)row*512 + t]       = o0;
    out[(size_t)row*512 + t + 256] = o1;
}

// ---------------- causal depthwise conv (K=4) + SiLU ----------------
__global__ __launch_bounds__(256) void conv_silu(
    const float* __restrict__ xz,    // [4100, 2048]; u = cols [0,1024)
    const float* __restrict__ cw,    // [1024, 4]
    const float* __restrict__ cb,    // [1024]
    float* __restrict__ uo)          // [4100, 1024]
{
    int idx = blockIdx.x*256 + threadIdx.x;   // 4100*1024 total
    int d = idx & 1023;
    int r = idx >> 10;
    int b = r / LSEQ, l = r % LSEQ;
    float acc = cb[d];
    #pragma unroll
    for (int k = 0; k < KCONV; ++k) {
        int ls = l - (KCONV-1) + k;
        if (ls >= 0) acc = fmaf(cw[d*KCONV + k], xz[((size_t)(b*LSEQ + ls))*2048 + d], acc);
    }
    uo[idx] = acc * sigmoidf_(acc);
}

// ---------------- selective scan, fused dA/dBu + gating ----------------
// grid (4, 64); block 256 = 16 d x 16 n. Chunk-stage 16 timesteps into LDS.
__global__ __launch_bounds__(256) void scan_kernel(
    const float* __restrict__ delta, // [4100, 1024]
    const float* __restrict__ u,     // [4100, 1024]
    const float* __restrict__ xdbl,  // [4100, 64]: B at +32, C at +48
    const float* __restrict__ xz,    // [4100, 2048]: z at +1024
    const float* __restrict__ A_log, // [1024, 16]
    const float* __restrict__ Dp,    // [1024]
    float* __restrict__ y)           // [4100, 1024]
{
    int b  = blockIdx.x;
    int d0 = blockIdx.y * 16;
    int tid = threadIdx.x;
    int dl = tid >> 4, n = tid & 15;
    int d = d0 + dl;
    float Adn = -__expf(A_log[(size_t)d*DSTATE + n]);
    float Dd  = Dp[d];
    float h = 0.f;

    __shared__ float sdelta[16][16];  // [t][dl]
    __shared__ float su[16][16];
    __shared__ float sz[16][16];
    __shared__ float sB[16][16];      // [t][n]
    __shared__ float sC[16][16];

    const size_t row0 = (size_t)b * LSEQ;
    int tl = tid >> 4, xx = tid & 15;

    for (int c0 = 0; c0 < LSEQ; c0 += 16) {
        int nt = min(16, LSEQ - c0);
        __syncthreads();   // protect LDS from overwrite while previous chunk computes
        if (tl < nt) {
            size_t row = row0 + c0 + tl;
            sdelta[tl][xx] = delta[row*DIN  + d0 + xx];
            su[tl][xx]     = u[row*DIN      + d0 + xx];
            sz[tl][xx]     = xz[row*2048 + DIN + d0 + xx];
            sB[tl][xx]     = xdbl[row*64 + DTRANK + xx];
            sC[tl][xx]     = xdbl[row*64 + DTRANK + DSTATE + xx];
        }
        __syncthreads();
        for (int t = 0; t < nt; ++t) {
            float dv = sdelta[t][dl];
            float uv = su[t][dl];
            float Bv = sB[t][n];
            float Cv = sC[t][n];
            float dA = __expf(dv * Adn);
            h = fmaf(dA, h, dv * uv * Bv);
            float p = h * Cv;
            p += __shfl_xor(p, 1);
            p += __shfl_xor(p, 2);
            p += __shfl_xor(p, 4);
            p += __shfl_xor(p, 8);
            if (n == 0) {
                float zv = sz[t][dl];
                y[(row0 + c0 + t)*DIN + d] = (p + uv*Dd) * (zv * sigmoidf_(zv));
            }
        }
    }
}

// ---------------- softmax over sequence + weighted pool ----------------
// grid (8, 4); block 256 = 4 l-lanes x 64 j
__global__ __launch_bounds__(256) void softpool(
    const float* __restrict__ a,   // [4100, 512]
    const float* __restrict__ yh,  // [4100, 512]
    float* __restrict__ pooled)    // [4, 512]
{
    int b  = blockIdx.y;
    int jj = threadIdx.x & 63;
    int j  = blockIdx.x * 64 + jj;
    int li = threadIdx.x >> 6;
    float m = -3.0e38f, s = 0.f, p = 0.f;
    for (int l = li; l < LSEQ; l += 4) {
        size_t off = ((size_t)(b*LSEQ + l))*OUTD + j;
        float av = a[off], yv = yh[off];
        float mn = fmaxf(m, av);
        float sc = __expf(m - mn);
        float e  = __expf(av - mn);
        s = s*sc + e;
        p = p*sc + yv*e;
        m = mn;
    }
    __shared__ float sm[4][64], ss[4][64], sp[4][64];
    sm[li][jj] = m; ss[li][jj] = s; sp[li][jj] = p;
    __syncthreads();
    if (li == 0) {
        #pragma unroll
        for (int k2 = 1; k2 < 4; ++k2) {
            float m2 = sm[k2][jj], s2 = ss[k2][jj], p2 = sp[k2][jj];
            float M2 = fmaxf(m, m2);
            float c1 = __expf(m - M2), c2 = __expf(m2 - M2);
            s = s*c1 + s2*c2;
            p = p*c1 + p2*c2;
            m = M2;
        }
        pooled[(size_t)b*OUTD + j] = p / s;
    }
}

extern "C" void kernel_launch(void* const* d_in, const int* in_sizes, int n_in,
                              void* d_out, int out_size, void* d_ws, size_t ws_size,
                              hipStream_t stream) {
    const float* img     = (const float*)d_in[0];
    const float* patch_W = (const float*)d_in[1];
    const float* patch_b = (const float*)d_in[2];
    const float* pos_emb = (const float*)d_in[3];
    const float* cls_tok = (const float*)d_in[4];
    const float* ln_w    = (const float*)d_in[5];
    const float* ln_b    = (const float*)d_in[6];
    const float* in_W    = (const float*)d_in[7];
    const float* conv_w  = (const float*)d_in[8];
    const float* conv_b  = (const float*)d_in[9];
    const float* xproj_W = (const float*)d_in[10];
    const float* dt_W    = (const float*)d_in[11];
    const float* dt_b    = (const float*)d_in[12];
    const float* A_log   = (const float*)d_in[13];
    const float* Dp      = (const float*)d_in[14];
    const float* out_W   = (const float*)d_in[15];
    const float* sl1_W   = (const float*)d_in[16];
    const float* sl1_b   = (const float*)d_in[17];
    const float* sl1_lnw = (const float*)d_in[18];
    const float* sl1_lnb = (const float*)d_in[19];
    const float* sl2_W   = (const float*)d_in[20];
    const float* sl2_b   = (const float*)d_in[21];
    const float* sl2_lnw = (const float*)d_in[22];
    const float* sl2_lnb = (const float*)d_in[23];
    const float* lat_lnw = (const float*)d_in[24];
    const float* lat_lnb = (const float*)d_in[25];
    float* out = (float*)d_out;
    float* ws  = (float*)d_ws;

    // workspace layout (floats): total ~25.5M floats = ~102 MB
    float* x     = ws;              // 4100*512  = 2,099,200
    float* xn    = x     + 2099200; // 4100*512
    float* xz    = xn    + 2099200; // 4100*2048 = 8,396,800
    float* u     = xz    + 8396800; // 4100*1024 = 4,198,400
    float* xdbl  = u     + 4198400; // 4100*64   =   262,400
    float* delta = xdbl  + 262400;  // 4100*1024
    float* y     = delta + 4198400; // 4100*1024
    // reuse: tmp_patch = y ; head: t1 = xz, yh = u, t2 = delta, a = y, pooled = xdbl

    // 1) patch embed GEMM -> tmp (y region), then assemble x with cls + pos
    gemm_f32<<<dim3(DIM/BN, (B_*NPATCH + BM-1)/BM), 256, 0, stream>>>(
        img, PDIM, patch_W, DIM, y, DIM, B_*NPATCH, DIM, PDIM, patch_b, nullptr, 0);
    assemble_x<<<(B_*LSEQ*DIM)/256, 256, 0, stream>>>(y, cls_tok, pos_emb, x);

    // 2) mamba blocks
    for (int i = 0; i < NBLK; ++i) {
        ln_act<<<MROWS, 256, 0, stream>>>(x, ln_w + i*DIM, ln_b + i*DIM, xn, 0);
        gemm_f32<<<dim3(2*DIN/BN, (MROWS+BM-1)/BM), 256, 0, stream>>>(
            xn, DIM, in_W + (size_t)i*DIM*2*DIN, 2*DIN, xz, 2*DIN,
            MROWS, 2*DIN, DIM, nullptr, nullptr, 0);
        conv_silu<<<(MROWS*DIN)/256, 256, 0, stream>>>(
            xz, conv_w + i*DIN*KCONV, conv_b + i*DIN, u);
        gemm_f32<<<dim3(1, (MROWS+BM-1)/BM), 256, 0, stream>>>(
            u, DIN, xproj_W + (size_t)i*DIN*64, 64, xdbl, 64,
            MROWS, 64, DIN, nullptr, nullptr, 0);
        gemm_f32<<<dim3(DIN/BN, (MROWS+BM-1)/BM), 256, 0, stream>>>(
            xdbl, 64, dt_W + (size_t)i*DTRANK*DIN, DIN, delta, DIN,
            MROWS, DIN, DTRANK, dt_b + i*DIN, nullptr, 1);
        scan_kernel<<<dim3(B_, DIN/16), 256, 0, stream>>>(
            delta, u, xdbl, xz, A_log + (size_t)i*DIN*DSTATE, Dp + i*DIN, y);
        gemm_f32<<<dim3(DIM/BN, (MROWS+BM-1)/BM), 256, 0, stream>>>(
            y, DIN, out_W + (size_t)i*DIN*DIM, DIM, x, DIM,
            MROWS, DIM, DIN, nullptr, x, 0);   // residual add
    }

    // 3) head
    gemm_f32<<<dim3(OUTD/BN, (MROWS+BM-1)/BM), 256, 0, stream>>>(
        x, DIM, sl1_W, OUTD, xz /*t1*/, OUTD, MROWS, OUTD, DIM, sl1_b, nullptr, 0);
    ln_act<<<MROWS, 256, 0, stream>>>(xz, sl1_lnw, sl1_lnb, u /*yh*/, 2);
    gemm_f32<<<dim3(OUTD/BN, (MROWS+BM-1)/BM), 256, 0, stream>>>(
        u, OUTD, sl2_W, OUTD, delta /*t2*/, OUTD, MROWS, OUTD, OUTD, sl2_b, nullptr, 0);
    ln_act<<<MROWS, 256, 0, stream>>>(delta, sl2_lnw, sl2_lnb, y /*a*/, 2);
    softpool<<<dim3(OUTD/64, B_), 256, 0, stream>>>(y, u, xdbl /*pooled*/);
    ln_act<<<B_, 256, 0, stream>>>(xdbl, lat_lnw, lat_lnb, out, 0);
}

// Round 3
// 994.548 us; speedup vs baseline: 1.5858x; 1.5858x over previous
//
#include <hip/hip_runtime.h>
#include <cstdint>
#include <cstddef>

#define B_     4
#define NPATCH 1024
#define LSEQ   1025
#define PDIM   768
#define DIM    512
#define OUTD   512
#define DIN    1024
#define DSTATE 16
#define DTRANK 32
#define KCONV  4
#define NBLK   2
#define MROWS  (B_*LSEQ)   // 4100
#define MPAD   4224

typedef unsigned short u16;
typedef __attribute__((ext_vector_type(8))) short bf16x8;
typedef __attribute__((ext_vector_type(4))) float f32x4;

__device__ __forceinline__ float sigmoidf_(float x){ return 1.f/(1.f+__expf(-x)); }
__device__ __forceinline__ float geluf_(float x){ return 0.5f*x*(1.f+erff(x*0.70710678118654752f)); }
__device__ __forceinline__ u16 f2bf(float x){
    uint32_t b = __float_as_uint(x);
    b += 0x7FFFu + ((b >> 16) & 1u);   // round-to-nearest-even (finite inputs)
    return (u16)(b >> 16);
}
template<int CTRL>
__device__ __forceinline__ float dppmov(float x){
    return __int_as_float(__builtin_amdgcn_update_dpp(0, __float_as_int(x), CTRL, 0xF, 0xF, true));
}
// sum across each 16-lane group (valid because butterfly makes quads/octs uniform)
__device__ __forceinline__ float red16(float p){
    p += dppmov<0xB1>(p);   // quad_perm xor1
    p += dppmov<0x4E>(p);   // quad_perm xor2
    p += dppmov<0x141>(p);  // row_half_mirror (== xor4 after quad sums)
    p += dppmov<0x140>(p);  // row_mirror      (== xor8 after oct sums)
    return p;
}
__device__ __forceinline__ void gload16(const void* g, void* l){
    __builtin_amdgcn_global_load_lds((const __attribute__((address_space(1))) void*)g,
                                     (__attribute__((address_space(3))) void*)l, 16, 0, 0);
}

// =============== bf16 MFMA NT GEMM: C[M,N]f32 = A[M,K]bf16 @ Wt[N,K]bf16^T ===============
// tile: BM = MF*32 rows x 128 cols, 4 waves (2m x 2n), wave tile = MF*16 x 64.
// act: 0=none, 1=softplus
template<int MF>
__global__ __launch_bounds__(256) void gemm_mfma(
    const u16* __restrict__ A, int lda,
    const u16* __restrict__ Wt,          // [N][K]
    float* __restrict__ C, int ldc,
    int M, int N, int K,
    const float* __restrict__ bias,
    const float* __restrict__ addsrc,
    int act)
{
    __shared__ u16 lsA[MF*32*32];        // [BM][32]
    __shared__ u16 lsB[128*32];          // [128][32]
    const int tid = threadIdx.x;
    const int wid = tid >> 6, lane = tid & 63;
    const int m0 = blockIdx.y * (MF*32), n0 = blockIdx.x * 128;
    const int wm = (wid>>1)*(MF*16), wn = (wid&1)*64;
    f32x4 acc[MF][4] = {};

    const char* Agp = (const char*)(A + (size_t)m0 * lda);
    const char* Bgp = (const char*)(Wt + (size_t)n0 * K);
    const int lrow = lane >> 2;                 // 0..15
    const int lcb  = (lane & 3) * 16;           // byte col within 64B slice

    for (int k0 = 0; k0 < K; k0 += 32) {
        // stage A (BM x 32) : rows-per-wave = MF*8
        {
            int ra = wid*(MF*8) + lrow;
            gload16(Agp + (size_t)ra*(lda*2) + k0*2 + lcb, &lsA[(wid*(MF*8))*32]);
            if constexpr (MF == 4) {
                gload16(Agp + (size_t)(ra+16)*(lda*2) + k0*2 + lcb, &lsA[(wid*(MF*8)+16)*32]);
            }
        }
        // stage B (128 x 32) : 32 rows per wave
        {
            int rb = wid*32 + lrow;
            gload16(Bgp + (size_t)rb*(K*2) + k0*2 + lcb, &lsB[(wid*32)*32]);
            gload16(Bgp + (size_t)(rb+16)*(K*2) + k0*2 + lcb, &lsB[(wid*32+16)*32]);
        }
        __syncthreads();
        bf16x8 af[MF], bfr[4];
        #pragma unroll
        for (int i = 0; i < MF; ++i)
            af[i] = *(const bf16x8*)&lsA[(wm + i*16 + (lane&15))*32 + (lane>>4)*8];
        #pragma unroll
        for (int j = 0; j < 4; ++j)
            bfr[j] = *(const bf16x8*)&lsB[(wn + j*16 + (lane&15))*32 + (lane>>4)*8];
        #pragma unroll
        for (int i = 0; i < MF; ++i)
            #pragma unroll
            for (int j = 0; j < 4; ++j)
                acc[i][j] = __builtin_amdgcn_mfma_f32_16x16x32_bf16(af[i], bfr[j], acc[i][j], 0, 0, 0);
        __syncthreads();
    }
    // epilogue: C/D layout col=lane&15, row=(lane>>4)*4+r
    #pragma unroll
    for (int i = 0; i < MF; ++i) {
        #pragma unroll
        for (int j = 0; j < 4; ++j) {
            int col = n0 + wn + j*16 + (lane & 15);
            float bv = bias ? bias[col] : 0.f;
            #pragma unroll
            for (int r = 0; r < 4; ++r) {
                int row = m0 + wm + i*16 + (lane>>4)*4 + r;
                if (row < M) {
                    float v = acc[i][j][r] + bv;
                    if (addsrc) v += addsrc[(size_t)row*ldc + col];
                    if (act == 1) v = (v > 20.f) ? v : log1pf(__expf(v));
                    C[(size_t)row*ldc + col] = v;
                }
            }
        }
    }
}

// =============== f32 GEMM (kept for xproj N=64) ===============
#define BMf 64
#define BNf 64
#define BKf 16
__global__ __launch_bounds__(256) void gemm_f32(
    const float* __restrict__ A, int lda,
    const float* __restrict__ W, int ldw,
    float* __restrict__ C, int ldc,
    int M, int N, int K,
    const float* __restrict__ bias,
    const float* __restrict__ addsrc,
    int act, u16* __restrict__ bf16out)
{
    __shared__ float As[BKf][BMf+4];
    __shared__ float Bs[BKf][BNf+4];
    int tid = threadIdx.x;
    int tx = tid & 15, ty = tid >> 4;
    int m0 = blockIdx.y * BMf, n0 = blockIdx.x * BNf;
    float acc[4][4] = {};
    for (int k0 = 0; k0 < K; k0 += BKf) {
        {
            int r  = tid >> 2;
            int kq = (tid & 3) << 2;
            float4 va = make_float4(0.f,0.f,0.f,0.f);
            int gr = m0 + r;
            if (gr < M) va = *reinterpret_cast<const float4*>(A + (size_t)gr*lda + k0 + kq);
            As[kq+0][r]=va.x; As[kq+1][r]=va.y; As[kq+2][r]=va.z; As[kq+3][r]=va.w;
        }
        {
            int kk = tid >> 4;
            int nq = (tid & 15) << 2;
            float4 vb = *reinterpret_cast<const float4*>(W + (size_t)(k0+kk)*ldw + n0 + nq);
            Bs[kk][nq+0]=vb.x; Bs[kk][nq+1]=vb.y; Bs[kk][nq+2]=vb.z; Bs[kk][nq+3]=vb.w;
        }
        __syncthreads();
        #pragma unroll
        for (int k = 0; k < BKf; ++k) {
            float a0=As[k][ty*4+0],a1=As[k][ty*4+1],a2=As[k][ty*4+2],a3=As[k][ty*4+3];
            float b0=Bs[k][tx*4+0],b1=Bs[k][tx*4+1],b2=Bs[k][tx*4+2],b3=Bs[k][tx*4+3];
            acc[0][0]=fmaf(a0,b0,acc[0][0]); acc[0][1]=fmaf(a0,b1,acc[0][1]);
            acc[0][2]=fmaf(a0,b2,acc[0][2]); acc[0][3]=fmaf(a0,b3,acc[0][3]);
            acc[1][0]=fmaf(a1,b0,acc[1][0]); acc[1][1]=fmaf(a1,b1,acc[1][1]);
            acc[1][2]=fmaf(a1,b2,acc[1][2]); acc[1][3]=fmaf(a1,b3,acc[1][3]);
            acc[2][0]=fmaf(a2,b0,acc[2][0]); acc[2][1]=fmaf(a2,b1,acc[2][1]);
            acc[2][2]=fmaf(a2,b2,acc[2][2]); acc[2][3]=fmaf(a2,b3,acc[2][3]);
            acc[3][0]=fmaf(a3,b0,acc[3][0]); acc[3][1]=fmaf(a3,b1,acc[3][1]);
            acc[3][2]=fmaf(a3,b2,acc[3][2]); acc[3][3]=fmaf(a3,b3,acc[3][3]);
        }
        __syncthreads();
    }
    #pragma unroll
    for (int i = 0; i < 4; ++i) {
        int r = m0 + ty*4 + i;
        if (r >= M) continue;
        #pragma unroll
        for (int j = 0; j < 4; ++j) {
            int c = n0 + tx*4 + j;
            float v = acc[i][j];
            if (bias)   v += bias[c];
            if (addsrc) v += addsrc[(size_t)r*ldc + c];
            if (act == 1) v = (v > 20.f) ? v : log1pf(__expf(v));
            C[(size_t)r*ldc + c] = v;
            if (bf16out) bf16out[(size_t)r*ldc + c] = f2bf(v);
        }
    }
}

// =============== prep: img cast + weight transpose-casts ===============
__device__ void tcast(const float* __restrict__ in, u16* __restrict__ outp,
                      int K, int N, int tix)
{
    __shared__ float tl[32][33];
    int ntn = N >> 5;
    int tk = tix / ntn, tn = tix - tk*ntn;
    int tid = threadIdx.x;
    int r = tid >> 3, c0 = (tid & 7) << 2;
    float4 v = *(const float4*)&in[(size_t)(tk*32 + r)*N + tn*32 + c0];
    tl[r][c0+0]=v.x; tl[r][c0+1]=v.y; tl[r][c0+2]=v.z; tl[r][c0+3]=v.w;
    __syncthreads();
    int nn = r, k0 = c0;
    uint32_t w0 = f2bf(tl[k0+0][nn]) | ((uint32_t)f2bf(tl[k0+1][nn]) << 16);
    uint32_t w1 = f2bf(tl[k0+2][nn]) | ((uint32_t)f2bf(tl[k0+3][nn]) << 16);
    uint2 o; o.x = w0; o.y = w1;
    *(uint2*)&outp[(size_t)(tn*32 + nn)*K + tk*32 + k0] = o;
}

__global__ __launch_bounds__(256) void prep_kernel(
    const float* __restrict__ img, const float* __restrict__ pW,
    const float* __restrict__ inW, const float* __restrict__ outW,
    const float* __restrict__ dtW, const float* __restrict__ s1W,
    const float* __restrict__ s2W,
    u16* imgb, u16* pWt, u16* inWt, u16* outWt, u16* dtWt, u16* s1t, u16* s2t)
{
    int b = blockIdx.x;
    if (b < 3072) {   // img cast: 4096*768 = 3,145,728 = 3072*1024
        int idx = b*1024 + threadIdx.x*4;
        float4 v = *(const float4*)&img[idx];
        uint2 o;
        o.x = f2bf(v.x) | ((uint32_t)f2bf(v.y) << 16);
        o.y = f2bf(v.z) | ((uint32_t)f2bf(v.w) << 16);
        *(uint2*)&imgb[idx] = o;
        return;
    }
    b -= 3072;
    if (b < 384)  { tcast(pW, pWt, 768, 512, b); return; }
    b -= 384;
    if (b < 2048) { int blk=b>>10, t=b&1023; tcast(inW + (size_t)blk*512*2048, inWt + (size_t)blk*1048576, 512, 2048, t); return; }
    b -= 2048;
    if (b < 1024) { int blk=b>>9, t=b&511; tcast(outW + (size_t)blk*1024*512, outWt + (size_t)blk*524288, 1024, 512, t); return; }
    b -= 1024;
    if (b < 64)   { int blk=b>>5, t=b&31; tcast(dtW + (size_t)blk*32*1024, dtWt + (size_t)blk*32768, 32, 1024, t); return; }
    b -= 64;
    if (b < 256)  { tcast(s1W, s1t, 512, 512, b); return; }
    b -= 256;
    tcast(s2W, s2t, 512, 512, b);
}

__global__ __launch_bounds__(256) void cast_bf16_k(const float* __restrict__ s, u16* __restrict__ dst){
    int idx = (blockIdx.x*256 + threadIdx.x)*4;
    float4 v = *(const float4*)&s[idx];
    uint2 o;
    o.x = f2bf(v.x) | ((uint32_t)f2bf(v.y) << 16);
    o.y = f2bf(v.z) | ((uint32_t)f2bf(v.w) << 16);
    *(uint2*)&dst[idx] = o;
}

// =============== assemble x = concat(cls, patches) + pos ===============
__global__ __launch_bounds__(256) void assemble_x(
    const float* __restrict__ tmp, const float* __restrict__ cls,
    const float* __restrict__ pos, float* __restrict__ x)
{
    int idx = blockIdx.x*256 + threadIdx.x;
    int d = idx & 511;
    int r = idx >> 9;
    int l = r % LSEQ;
    int b = r / LSEQ;
    float v = (l == 0) ? cls[d] : tmp[((size_t)(b*NPATCH + l-1))*DIM + d];
    x[idx] = v + pos[(size_t)l*DIM + d];
}

// =============== row LayerNorm (+gelu), 512 cols, dual f32/bf16 outputs ===============
__global__ __launch_bounds__(256) void ln_act(
    const float* __restrict__ in, const float* __restrict__ gw, const float* __restrict__ gb,
    float* __restrict__ f32out, u16* __restrict__ bf16out, int act)
{
    int row = blockIdx.x;
    const float* p = in + (size_t)row * 512;
    int t = threadIdx.x;
    float v0 = p[t], v1 = p[t + 256];
    float s = v0 + v1, q = v0*v0 + v1*v1;
    #pragma unroll
    for (int o = 32; o; o >>= 1) { s += __shfl_xor(s, o); q += __shfl_xor(q, o); }
    __shared__ float ls[4], lq[4];
    int w = t >> 6;
    if ((t & 63) == 0) { ls[w] = s; lq[w] = q; }
    __syncthreads();
    s = ls[0]+ls[1]+ls[2]+ls[3];
    q = lq[0]+lq[1]+lq[2]+lq[3];
    float mean = s * (1.f/512.f);
    float var  = q * (1.f/512.f) - mean*mean;
    float inv  = rsqrtf(var + 1e-5f);
    float o0 = (v0-mean)*inv*gw[t]     + gb[t];
    float o1 = (v1-mean)*inv*gw[t+256] + gb[t+256];
    if (act == 2) { o0 = geluf_(o0); o1 = geluf_(o1); }
    if (f32out)  { f32out[(size_t)row*512 + t] = o0; f32out[(size_t)row*512 + t + 256] = o1; }
    if (bf16out) { bf16out[(size_t)row*512 + t] = f2bf(o0); bf16out[(size_t)row*512 + t + 256] = f2bf(o1); }
}

// =============== causal depthwise conv (K=4) + SiLU ===============
__global__ __launch_bounds__(256) void conv_silu(
    const float* __restrict__ xz, const float* __restrict__ cw,
    const float* __restrict__ cb, float* __restrict__ uo)
{
    int idx = blockIdx.x*256 + threadIdx.x;
    int d = idx & 1023;
    int r = idx >> 10;
    int b = r / LSEQ, l = r % LSEQ;
    float acc = cb[d];
    #pragma unroll
    for (int k = 0; k < KCONV; ++k) {
        int ls = l - (KCONV-1) + k;
        if (ls >= 0) acc = fmaf(cw[d*KCONV + k], xz[((size_t)(b*LSEQ + ls))*2048 + d], acc);
    }
    uo[idx] = acc * sigmoidf_(acc);
}

// =============== selective scan: 1024 blocks x 64 threads, DPP reduce, dbuf LDS ===============
__global__ __launch_bounds__(64) void scan_kernel(
    const float* __restrict__ delta, const float* __restrict__ u,
    const float* __restrict__ xdbl,  const float* __restrict__ xz,
    const float* __restrict__ A_log, const float* __restrict__ Dp,
    u16* __restrict__ yb)      // bf16 out [4100(+pad)][1024]
{
    const int dgi  = blockIdx.x;       // 0..255
    const int b    = blockIdx.y;       // 0..3
    const int lane = threadIdx.x;      // 0..63
    const int dl = lane >> 4, n = lane & 15;
    const int d0 = dgi * 4;
    const int d  = d0 + dl;
    const size_t row0 = (size_t)b * LSEQ;
    const float Adn = -__expf(A_log[(size_t)d*DSTATE + n]);
    const float Dd  = Dp[d];
    float h = 0.f;

    __shared__ float sD[2][4][16];     // [buf][dl][t]
    __shared__ float sU[2][4][16];
    __shared__ float sZ[2][4][16];
    __shared__ float sB[2][16][16];    // [buf][t][n]
    __shared__ float sC[2][16][16];

    const int lt = lane & 15, ld2 = lane >> 4;   // loader lane roles
    float rD, rU, rZ, rB[4], rC[4];

    auto LOADC = [&](int c){
        size_t rw = row0 + (size_t)c*16;
        rD = delta[(rw + lt)*DIN + d0 + ld2];
        rU = u[(rw + lt)*DIN + d0 + ld2];
        rZ = xz[(rw + lt)*2048 + DIN + d0 + ld2];
        #pragma unroll
        for (int j = 0; j < 4; ++j){
            size_t r2 = rw + j*4 + ld2;
            rB[j] = xdbl[r2*64 + DTRANK + lt];
            rC[j] = xdbl[r2*64 + DTRANK + DSTATE + lt];
        }
    };
    auto WRITEC = [&](int pb){
        sD[pb][ld2][lt] = rD;
        sU[pb][ld2][lt] = rU;
        sZ[pb][ld2][lt] = rZ;
        #pragma unroll
        for (int j = 0; j < 4; ++j){ sB[pb][j*4+ld2][lt] = rB[j]; sC[pb][j*4+ld2][lt] = rC[j]; }
    };
    auto COMPUTE = [&](int pb, size_t rwbase){
        #pragma unroll
        for (int t = 0; t < 16; ++t){
            float dv = sD[pb][dl][t];
            float uv = sU[pb][dl][t];
            float Bv = sB[pb][t][n];
            float Cv = sC[pb][t][n];
            float dA = __expf(dv * Adn);
            h = fmaf(dA, h, dv * uv * Bv);
            float p = red16(h * Cv);
            if (n == 0){
                float zv = sZ[pb][dl][t];
                yb[(rwbase + t)*DIN + d] = f2bf((p + uv*Dd) * (zv * sigmoidf_(zv)));
            }
        }
    };

    LOADC(0); WRITEC(0);
    for (int c = 0; c < 63; ++c){
        LOADC(c+1);
        __syncthreads();
        COMPUTE(c & 1, row0 + (size_t)c*16);
        WRITEC((c+1) & 1);
    }
    __syncthreads();
    COMPUTE(1, row0 + 63*16);
    // tail: row 1024
    {
        size_t rw = row0 + 1024;
        float dv = delta[rw*DIN + d];
        float uv = u[rw*DIN + d];
        float zv = xz[rw*2048 + DIN + d];
        float Bv = xdbl[rw*64 + DTRANK + n];
        float Cv = xdbl[rw*64 + DTRANK + DSTATE + n];
        float dA = __expf(dv * Adn);
        h = fmaf(dA, h, dv * uv * Bv);
        float p = red16(h * Cv);
        if (n == 0)
            yb[rw*DIN + d] = f2bf((p + uv*Dd) * (zv * sigmoidf_(zv)));
    }
}

// =============== softmax over sequence + weighted pool ===============
__global__ __launch_bounds__(256) void softpool(
    const float* __restrict__ a, const float* __restrict__ yh,
    float* __restrict__ pooled)
{
    int b  = blockIdx.y;
    int jj = threadIdx.x & 63;
    int j  = blockIdx.x * 64 + jj;
    int li = threadIdx.x >> 6;
    float m = -3.0e38f, s = 0.f, p = 0.f;
    for (int l = li; l < LSEQ; l += 4) {
        size_t off = ((size_t)(b*LSEQ + l))*OUTD + j;
        float av = a[off], yv = yh[off];
        float mn = fmaxf(m, av);
        float sc = __expf(m - mn);
        float e  = __expf(av - mn);
        s = s*sc + e;
        p = p*sc + yv*e;
        m = mn;
    }
    __shared__ float sm[4][64], ss[4][64], sp[4][64];
    sm[li][jj] = m; ss[li][jj] = s; sp[li][jj] = p;
    __syncthreads();
    if (li == 0) {
        #pragma unroll
        for (int k2 = 1; k2 < 4; ++k2) {
            float m2 = sm[k2][jj], s2 = ss[k2][jj], p2 = sp[k2][jj];
            float M2 = fmaxf(m, m2);
            float c1 = __expf(m - M2), c2 = __expf(m2 - M2);
            s = s*c1 + s2*c2;
            p = p*c1 + p2*c2;
            m = M2;
        }
        pooled[(size_t)b*OUTD + j] = p / s;
    }
}

extern "C" void kernel_launch(void* const* d_in, const int* in_sizes, int n_in,
                              void* d_out, int out_size, void* d_ws, size_t ws_size,
                              hipStream_t stream) {
    const float* img     = (const float*)d_in[0];
    const float* patch_W = (const float*)d_in[1];
    const float* patch_b = (const float*)d_in[2];
    const float* pos_emb = (const float*)d_in[3];
    const float* cls_tok = (const float*)d_in[4];
    const float* ln_w    = (const float*)d_in[5];
    const float* ln_b    = (const float*)d_in[6];
    const float* in_W    = (const float*)d_in[7];
    const float* conv_w  = (const float*)d_in[8];
    const float* conv_b  = (const float*)d_in[9];
    const float* xproj_W = (const float*)d_in[10];
    const float* dt_W    = (const float*)d_in[11];
    const float* dt_b    = (const float*)d_in[12];
    const float* A_log   = (const float*)d_in[13];
    const float* Dp      = (const float*)d_in[14];
    const float* out_W   = (const float*)d_in[15];
    const float* sl1_W   = (const float*)d_in[16];
    const float* sl1_b   = (const float*)d_in[17];
    const float* sl1_lnw = (const float*)d_in[18];
    const float* sl1_lnb = (const float*)d_in[19];
    const float* sl2_W   = (const float*)d_in[20];
    const float* sl2_b   = (const float*)d_in[21];
    const float* sl2_lnw = (const float*)d_in[22];
    const float* sl2_lnb = (const float*)d_in[23];
    const float* lat_lnw = (const float*)d_in[24];
    const float* lat_lnb = (const float*)d_in[25];
    float* out = (float*)d_out;
    float* ws  = (float*)d_ws;

    // ---- f32 workspace (floats) ----
    float* x     = ws + 0;          // 2,099,200
    float* xz    = ws + 2099200;    // 8,396,800  (head: yh @ +0, t2 @ +2,099,200)
    float* u     = ws + 10496000;   // 4,198,400  (head: a)
    float* xdbl  = ws + 14694400;   //   262,400  (head: pooled)
    float* delta = ws + 14956800;   // 4,198,400  (patch tmp; head t1)
    // ---- bf16 workspace (u16), base after 19,155,200 floats ----
    u16* ub      = (u16*)(ws + 19155200);
    u16* regA    = ub + 0;          // 4,325,376 : img_bf / y_bf / yh_bf
    u16* regB    = ub + 4325376;    // 2,162,688 : xn_bf / x_bf
    u16* xdbl_bf = ub + 6488064;    //   270,336
    u16* pWt     = ub + 6758400;    //   393,216
    u16* inWt    = ub + 7151616;    // 2,097,152 (2 blocks)
    u16* outWt   = ub + 9248768;    // 1,048,576 (2 blocks)
    u16* dtWt    = ub + 10297344;   //    65,536 (2 blocks)
    u16* s1t     = ub + 10362880;   //   262,144
    u16* s2t     = ub + 10625024;   //   262,144
    // total = 76,620,800 + 21,774,336 bytes ≈ 98.4 MB

    float* yh     = xz;             // head reuse
    float* t2     = xz + 2099200;
    float* a      = u;
    float* pooled = xdbl;
    float* t1     = delta;

    // 0) prep: img cast + all weight transpose-casts
    prep_kernel<<<7104, 256, 0, stream>>>(img, patch_W, in_W, out_W, dt_W, sl1_W, sl2_W,
                                          regA /*img_bf*/, pWt, inWt, outWt, dtWt, s1t, s2t);

    // 1) patch GEMM (MFMA): [4096,768]x[768,512] -> tmp(delta region), + assemble
    gemm_mfma<2><<<dim3(512/128, 4096/64), 256, 0, stream>>>(
        regA, PDIM, pWt, delta, DIM, 4096, DIM, PDIM, patch_b, nullptr, 0);
    assemble_x<<<(MROWS*DIM)/256, 256, 0, stream>>>(delta, cls_tok, pos_emb, x);

    // 2) mamba blocks
    for (int i = 0; i < NBLK; ++i) {
        ln_act<<<MROWS, 256, 0, stream>>>(x, ln_w + i*DIM, ln_b + i*DIM,
                                          nullptr, regB /*xn_bf*/, 0);
        gemm_mfma<4><<<dim3(2048/128, 33), 256, 0, stream>>>(
            regB, DIM, inWt + (size_t)i*1048576, xz, 2*DIN,
            MROWS, 2*DIN, DIM, nullptr, nullptr, 0);
        conv_silu<<<(MROWS*DIN)/256, 256, 0, stream>>>(
            xz, conv_w + i*DIN*KCONV, conv_b + i*DIN, u);
        gemm_f32<<<dim3(1, 65), 256, 0, stream>>>(
            u, DIN, xproj_W + (size_t)i*DIN*64, 64, xdbl, 64,
            MROWS, 64, DIN, nullptr, nullptr, 0, xdbl_bf);
        gemm_mfma<2><<<dim3(1024/128, 65), 256, 0, stream>>>(
            xdbl_bf, 64, dtWt + (size_t)i*32768, delta, DIN,
            MROWS, DIN, DTRANK, dt_b + i*DIN, nullptr, 1);
        scan_kernel<<<dim3(256, 4), 64, 0, stream>>>(
            delta, u, xdbl, xz, A_log + (size_t)i*DIN*DSTATE, Dp + i*DIN,
            regA /*y_bf*/);
        gemm_mfma<2><<<dim3(512/128, 65), 256, 0, stream>>>(
            regA, DIN, outWt + (size_t)i*524288, x, DIM,
            MROWS, DIM, DIN, nullptr, x, 0);     // residual
    }

    // 3) head
    cast_bf16_k<<<2050, 256, 0, stream>>>(x, regB /*x_bf*/);
    gemm_mfma<2><<<dim3(512/128, 65), 256, 0, stream>>>(
        regB, DIM, s1t, t1, OUTD, MROWS, OUTD, DIM, sl1_b, nullptr, 0);
    ln_act<<<MROWS, 256, 0, stream>>>(t1, sl1_lnw, sl1_lnb, yh, regA /*yh_bf*/, 2);
    gemm_mfma<2><<<dim3(512/128, 65), 256, 0, stream>>>(
        regA, OUTD, s2t, t2, OUTD, MROWS, OUTD, OUTD, sl2_b, nullptr, 0);
    ln_act<<<MROWS, 256, 0, stream>>>(t2, sl2_lnw, sl2_lnb, a, nullptr, 2);
    softpool<<<dim3(OUTD/64, B_), 256, 0, stream>>>(a, yh, pooled);
    ln_act<<<B_, 256, 0, stream>>>(pooled, lat_lnw, lat_lnb, out, nullptr, 0);
}

// Round 4
// 690.310 us; speedup vs baseline: 2.2847x; 1.4407x over previous
//
#include <hip/hip_runtime.h>
#include <cstdint>
#include <cstddef>

#define B_     4
#define NPATCH 1024
#define LSEQ   1025
#define PDIM   768
#define DIM    512
#define OUTD   512
#define DIN    1024
#define DSTATE 16
#define DTRANK 32
#define KCONV  4
#define NBLK   2
#define MROWS  (B_*LSEQ)   // 4100

typedef unsigned short u16;
typedef __attribute__((ext_vector_type(8))) short bf16x8;
typedef __attribute__((ext_vector_type(4))) float f32x4;

__device__ __forceinline__ float sigmoidf_(float x){ return 1.f/(1.f+__expf(-x)); }
__device__ __forceinline__ float geluf_(float x){ return 0.5f*x*(1.f+erff(x*0.70710678118654752f)); }
__device__ __forceinline__ u16 f2bf(float x){
    uint32_t b = __float_as_uint(x);
    b += 0x7FFFu + ((b >> 16) & 1u);
    return (u16)(b >> 16);
}
template<int CTRL>
__device__ __forceinline__ float dppmov(float x){
    return __int_as_float(__builtin_amdgcn_update_dpp(0, __float_as_int(x), CTRL, 0xF, 0xF, true));
}
// sum across each 16-lane group
__device__ __forceinline__ float red16(float p){
    p += dppmov<0xB1>(p);   // quad_perm xor1
    p += dppmov<0x4E>(p);   // quad_perm xor2
    p += dppmov<0x141>(p);  // row_half_mirror
    p += dppmov<0x140>(p);  // row_mirror
    return p;
}
__device__ __forceinline__ void gload16(const void* g, void* l){
    __builtin_amdgcn_global_load_lds((const __attribute__((address_space(1))) void*)g,
                                     (__attribute__((address_space(3))) void*)l, 16, 0, 0);
}

// =============== bf16 MFMA NT GEMM: C[M,N]f32 = A[M,K]bf16 @ Wt[N,K]bf16^T ===============
// tile: BM = MF*32 rows x 128 cols, 4 waves (2m x 2n). act: 0=none, 1=softplus
template<int MF>
__global__ __launch_bounds__(256) void gemm_mfma(
    const u16* __restrict__ A, int lda,
    const u16* __restrict__ Wt,          // [N][K]
    float* __restrict__ C, int ldc,
    int M, int N, int K,
    const float* __restrict__ bias,
    const float* __restrict__ addsrc,
    int act, u16* __restrict__ bf16out)
{
    __shared__ u16 lsA[MF*32*32];        // [BM][32]
    __shared__ u16 lsB[128*32];          // [128][32]
    const int tid = threadIdx.x;
    const int wid = tid >> 6, lane = tid & 63;
    const int m0 = blockIdx.y * (MF*32), n0 = blockIdx.x * 128;
    const int wm = (wid>>1)*(MF*16), wn = (wid&1)*64;
    f32x4 acc[MF][4] = {};

    const char* Agp = (const char*)(A + (size_t)m0 * lda);
    const char* Bgp = (const char*)(Wt + (size_t)n0 * K);
    const int lrow = lane >> 2;
    const int lcb  = (lane & 3) * 16;

    for (int k0 = 0; k0 < K; k0 += 32) {
        {
            int ra = wid*(MF*8) + lrow;
            gload16(Agp + (size_t)ra*(lda*2) + k0*2 + lcb, &lsA[(wid*(MF*8))*32]);
            if constexpr (MF == 4) {
                gload16(Agp + (size_t)(ra+16)*(lda*2) + k0*2 + lcb, &lsA[(wid*(MF*8)+16)*32]);
            }
        }
        {
            int rb = wid*32 + lrow;
            gload16(Bgp + (size_t)rb*(K*2) + k0*2 + lcb, &lsB[(wid*32)*32]);
            gload16(Bgp + (size_t)(rb+16)*(K*2) + k0*2 + lcb, &lsB[(wid*32+16)*32]);
        }
        __syncthreads();
        bf16x8 af[MF], bfr[4];
        #pragma unroll
        for (int i = 0; i < MF; ++i)
            af[i] = *(const bf16x8*)&lsA[(wm + i*16 + (lane&15))*32 + (lane>>4)*8];
        #pragma unroll
        for (int j = 0; j < 4; ++j)
            bfr[j] = *(const bf16x8*)&lsB[(wn + j*16 + (lane&15))*32 + (lane>>4)*8];
        #pragma unroll
        for (int i = 0; i < MF; ++i)
            #pragma unroll
            for (int j = 0; j < 4; ++j)
                acc[i][j] = __builtin_amdgcn_mfma_f32_16x16x32_bf16(af[i], bfr[j], acc[i][j], 0, 0, 0);
        __syncthreads();
    }
    #pragma unroll
    for (int i = 0; i < MF; ++i) {
        #pragma unroll
        for (int j = 0; j < 4; ++j) {
            int col = n0 + wn + j*16 + (lane & 15);
            float bv = bias ? bias[col] : 0.f;
            #pragma unroll
            for (int r = 0; r < 4; ++r) {
                int row = m0 + wm + i*16 + (lane>>4)*4 + r;
                if (row < M) {
                    float v = acc[i][j][r] + bv;
                    if (addsrc) v += addsrc[(size_t)row*ldc + col];
                    if (act == 1) v = (v > 20.f) ? v : log1pf(__expf(v));
                    C[(size_t)row*ldc + col] = v;
                    if (bf16out) bf16out[(size_t)row*ldc + col] = f2bf(v);
                }
            }
        }
    }
}

// =============== xproj split-K f32 GEMM: P[kc][4100][64] partials ===============
// grid (65, 4): block = 64 rows x 64 cols, K-chunk = 256
__global__ __launch_bounds__(256) void xproj_gemm(
    const float* __restrict__ Au,      // [4100][1024]
    const float* __restrict__ W,       // [1024][64]
    float* __restrict__ P)
{
    __shared__ float As[16][68];
    __shared__ float Bs[16][68];
    int tid = threadIdx.x;
    int tx = tid & 15, ty = tid >> 4;
    int m0 = blockIdx.x * 64;
    int kbase = blockIdx.y * 256;
    float acc[4][4] = {};
    for (int k0 = kbase; k0 < kbase + 256; k0 += 16) {
        {
            int r  = tid >> 2;
            int kq = (tid & 3) << 2;
            float4 va = make_float4(0.f,0.f,0.f,0.f);
            int gr = m0 + r;
            if (gr < MROWS) va = *reinterpret_cast<const float4*>(Au + (size_t)gr*DIN + k0 + kq);
            As[kq+0][r]=va.x; As[kq+1][r]=va.y; As[kq+2][r]=va.z; As[kq+3][r]=va.w;
        }
        {
            int kk = tid >> 4;
            int nq = (tid & 15) << 2;
            float4 vb = *reinterpret_cast<const float4*>(W + (size_t)(k0+kk)*64 + nq);
            Bs[kk][nq+0]=vb.x; Bs[kk][nq+1]=vb.y; Bs[kk][nq+2]=vb.z; Bs[kk][nq+3]=vb.w;
        }
        __syncthreads();
        #pragma unroll
        for (int k = 0; k < 16; ++k) {
            float a0=As[k][ty*4+0],a1=As[k][ty*4+1],a2=As[k][ty*4+2],a3=As[k][ty*4+3];
            float b0=Bs[k][tx*4+0],b1=Bs[k][tx*4+1],b2=Bs[k][tx*4+2],b3=Bs[k][tx*4+3];
            acc[0][0]=fmaf(a0,b0,acc[0][0]); acc[0][1]=fmaf(a0,b1,acc[0][1]);
            acc[0][2]=fmaf(a0,b2,acc[0][2]); acc[0][3]=fmaf(a0,b3,acc[0][3]);
            acc[1][0]=fmaf(a1,b0,acc[1][0]); acc[1][1]=fmaf(a1,b1,acc[1][1]);
            acc[1][2]=fmaf(a1,b2,acc[1][2]); acc[1][3]=fmaf(a1,b3,acc[1][3]);
            acc[2][0]=fmaf(a2,b0,acc[2][0]); acc[2][1]=fmaf(a2,b1,acc[2][1]);
            acc[2][2]=fmaf(a2,b2,acc[2][2]); acc[2][3]=fmaf(a2,b3,acc[2][3]);
            acc[3][0]=fmaf(a3,b0,acc[3][0]); acc[3][1]=fmaf(a3,b1,acc[3][1]);
            acc[3][2]=fmaf(a3,b2,acc[3][2]); acc[3][3]=fmaf(a3,b3,acc[3][3]);
        }
        __syncthreads();
    }
    float* Pp = P + (size_t)blockIdx.y * (MROWS*64);
    #pragma unroll
    for (int i = 0; i < 4; ++i) {
        int r = m0 + ty*4 + i;
        if (r >= MROWS) continue;
        #pragma unroll
        for (int j = 0; j < 4; ++j)
            Pp[(size_t)r*64 + tx*4 + j] = acc[i][j];
    }
}

__global__ __launch_bounds__(256) void xproj_reduce(
    const float* __restrict__ P, float* __restrict__ xdbl, u16* __restrict__ xdbl_bf)
{
    int idx = blockIdx.x*256 + threadIdx.x;      // 262400 total
    float v = P[idx] + P[MROWS*64 + idx] + P[2*MROWS*64 + idx] + P[3*MROWS*64 + idx];
    xdbl[idx] = v;
    xdbl_bf[idx] = f2bf(v);
}

// =============== prep: img cast + weight transpose-casts ===============
__device__ void tcast(const float* __restrict__ in, u16* __restrict__ outp,
                      int K, int N, int tix)
{
    __shared__ float tl[32][33];
    int ntn = N >> 5;
    int tk = tix / ntn, tn = tix - tk*ntn;
    int tid = threadIdx.x;
    int r = tid >> 3, c0 = (tid & 7) << 2;
    float4 v = *(const float4*)&in[(size_t)(tk*32 + r)*N + tn*32 + c0];
    tl[r][c0+0]=v.x; tl[r][c0+1]=v.y; tl[r][c0+2]=v.z; tl[r][c0+3]=v.w;
    __syncthreads();
    int nn = r, k0 = c0;
    uint32_t w0 = f2bf(tl[k0+0][nn]) | ((uint32_t)f2bf(tl[k0+1][nn]) << 16);
    uint32_t w1 = f2bf(tl[k0+2][nn]) | ((uint32_t)f2bf(tl[k0+3][nn]) << 16);
    uint2 o; o.x = w0; o.y = w1;
    *(uint2*)&outp[(size_t)(tn*32 + nn)*K + tk*32 + k0] = o;
}

__global__ __launch_bounds__(256) void prep_kernel(
    const float* __restrict__ img, const float* __restrict__ pW,
    const float* __restrict__ inW, const float* __restrict__ outW,
    const float* __restrict__ dtW, const float* __restrict__ s1W,
    const float* __restrict__ s2W,
    u16* imgb, u16* pWt, u16* inWt, u16* outWt, u16* dtWt, u16* s1t, u16* s2t)
{
    int b = blockIdx.x;
    if (b < 3072) {
        int idx = b*1024 + threadIdx.x*4;
        float4 v = *(const float4*)&img[idx];
        uint2 o;
        o.x = f2bf(v.x) | ((uint32_t)f2bf(v.y) << 16);
        o.y = f2bf(v.z) | ((uint32_t)f2bf(v.w) << 16);
        *(uint2*)&imgb[idx] = o;
        return;
    }
    b -= 3072;
    if (b < 384)  { tcast(pW, pWt, 768, 512, b); return; }
    b -= 384;
    if (b < 2048) { int blk=b>>10, t=b&1023; tcast(inW + (size_t)blk*512*2048, inWt + (size_t)blk*1048576, 512, 2048, t); return; }
    b -= 2048;
    if (b < 1024) { int blk=b>>9, t=b&511; tcast(outW + (size_t)blk*1024*512, outWt + (size_t)blk*524288, 1024, 512, t); return; }
    b -= 1024;
    if (b < 64)   { int blk=b>>5, t=b&31; tcast(dtW + (size_t)blk*32*1024, dtWt + (size_t)blk*32768, 32, 1024, t); return; }
    b -= 64;
    if (b < 256)  { tcast(s1W, s1t, 512, 512, b); return; }
    b -= 256;
    tcast(s2W, s2t, 512, 512, b);
}

// =============== assemble x = concat(cls, patches) + pos ===============
__global__ __launch_bounds__(256) void assemble_x(
    const float* __restrict__ tmp, const float* __restrict__ cls,
    const float* __restrict__ pos, float* __restrict__ x)
{
    int idx = blockIdx.x*256 + threadIdx.x;
    int d = idx & 511;
    int r = idx >> 9;
    int l = r % LSEQ;
    int b = r / LSEQ;
    float v = (l == 0) ? cls[d] : tmp[((size_t)(b*NPATCH + l-1))*DIM + d];
    x[idx] = v + pos[(size_t)l*DIM + d];
}

// =============== row LayerNorm (+gelu), 512 cols, dual f32/bf16 outputs ===============
__global__ __launch_bounds__(256) void ln_act(
    const float* __restrict__ in, const float* __restrict__ gw, const float* __restrict__ gb,
    float* __restrict__ f32out, u16* __restrict__ bf16out, int act)
{
    int row = blockIdx.x;
    const float* p = in + (size_t)row * 512;
    int t = threadIdx.x;
    float v0 = p[t], v1 = p[t + 256];
    float s = v0 + v1, q = v0*v0 + v1*v1;
    #pragma unroll
    for (int o = 32; o; o >>= 1) { s += __shfl_xor(s, o); q += __shfl_xor(q, o); }
    __shared__ float ls[4], lq[4];
    int w = t >> 6;
    if ((t & 63) == 0) { ls[w] = s; lq[w] = q; }
    __syncthreads();
    s = ls[0]+ls[1]+ls[2]+ls[3];
    q = lq[0]+lq[1]+lq[2]+lq[3];
    float mean = s * (1.f/512.f);
    float var  = q * (1.f/512.f) - mean*mean;
    float inv  = rsqrtf(var + 1e-5f);
    float o0 = (v0-mean)*inv*gw[t]     + gb[t];
    float o1 = (v1-mean)*inv*gw[t+256] + gb[t+256];
    if (act == 2) { o0 = geluf_(o0); o1 = geluf_(o1); }
    if (f32out)  { f32out[(size_t)row*512 + t] = o0; f32out[(size_t)row*512 + t + 256] = o1; }
    if (bf16out) { bf16out[(size_t)row*512 + t] = f2bf(o0); bf16out[(size_t)row*512 + t + 256] = f2bf(o1); }
}

// =============== causal depthwise conv (K=4) + SiLU ===============
__global__ __launch_bounds__(256) void conv_silu(
    const float* __restrict__ xz, const float* __restrict__ cw,
    const float* __restrict__ cb, float* __restrict__ uo)
{
    int idx = blockIdx.x*256 + threadIdx.x;
    int d = idx & 1023;
    int r = idx >> 10;
    int b = r / LSEQ, l = r % LSEQ;
    float acc = cb[d];
    #pragma unroll
    for (int k = 0; k < KCONV; ++k) {
        int ls = l - (KCONV-1) + k;
        if (ls >= 0) acc = fmaf(cw[d*KCONV + k], xz[((size_t)(b*LSEQ + ls))*2048 + d], acc);
    }
    uo[idx] = acc * sigmoidf_(acc);
}

// =============== segmented selective scan ===============
// Phase 1: segments 0..6 (128 rows each) compute (prod dA, h-scan from 0).
// grid (64, 4, 7), block 256 = 16 d x 16 n.
__global__ __launch_bounds__(256) void scan_phase1(
    const float* __restrict__ delta, const float* __restrict__ u,
    const float* __restrict__ xdbl,  const float* __restrict__ A_log,
    float* __restrict__ Aseg, float* __restrict__ Hseg)
{
    const int dg = blockIdx.x, b = blockIdx.y, s = blockIdx.z;
    const int tid = threadIdx.x;
    const int n = tid & 15, dl = tid >> 4;
    const int d0 = dg*16, d = d0 + dl;
    const float Adn = -__expf(A_log[(size_t)d*DSTATE + n]);
    float ap = 1.f, h = 0.f;
    __shared__ float sD[16][16], sU[16][16], sB[16][16];
    const size_t base = (size_t)b*LSEQ + (size_t)s*128;
    for (int c0 = 0; c0 < 128; c0 += 16) {
        __syncthreads();
        {
            int tr = tid >> 4, tc = tid & 15;
            size_t row = base + c0 + tr;
            sD[tr][tc] = delta[row*DIN + d0+tc];
            sU[tr][tc] = u[row*DIN + d0+tc];
            sB[tr][tc] = xdbl[row*64 + DTRANK + tc];
        }
        __syncthreads();
        #pragma unroll
        for (int t = 0; t < 16; ++t) {
            float dv = sD[t][dl], uv = sU[t][dl], Bv = sB[t][n];
            float dA = __expf(dv * Adn);
            ap *= dA;
            h = fmaf(dA, h, dv*uv*Bv);
        }
    }
    int dn = d*DSTATE + n;
    Aseg[((size_t)b*7 + s)*16384 + dn] = ap;
    Hseg[((size_t)b*8 + s)*16384 + dn] = h;
}

// Phase mid: compose entry states in place: Hseg[s] := H0[s]
__global__ __launch_bounds__(256) void scan_mid(
    float* __restrict__ Hseg, const float* __restrict__ Aseg)
{
    int idx = blockIdx.x*256 + threadIdx.x;      // 65536 = 4 * 16384
    int b = idx >> 14, dn = idx & 16383;
    float prev = 0.f;
    #pragma unroll
    for (int s = 0; s < 7; ++s) {
        size_t offH = ((size_t)b*8 + s)*16384 + dn;
        float a  = Aseg[((size_t)b*7 + s)*16384 + dn];
        float hs = Hseg[offH];
        Hseg[offH] = prev;
        prev = fmaf(a, prev, hs);
    }
    Hseg[((size_t)b*8 + 7)*16384 + dn] = prev;
}

// Phase 2: re-scan each segment from its entry state, emit gated y (bf16).
// grid (64, 4, 8), block 256 = 16 d x 16 n. Seg 7 handles tail row 1024.
__global__ __launch_bounds__(256) void scan_phase2(
    const float* __restrict__ delta, const float* __restrict__ u,
    const float* __restrict__ xdbl,  const float* __restrict__ xz,
    const float* __restrict__ A_log, const float* __restrict__ Dp,
    const float* __restrict__ H0, u16* __restrict__ yb)
{
    const int dg = blockIdx.x, b = blockIdx.y, s = blockIdx.z;
    const int tid = threadIdx.x;
    const int n = tid & 15, dl = tid >> 4;
    const int d0 = dg*16, d = d0 + dl;
    const float Adn = -__expf(A_log[(size_t)d*DSTATE + n]);
    const float Dd = Dp[d];
    float h = H0[((size_t)b*8 + s)*16384 + d*DSTATE + n];
    __shared__ float sD[16][16], sU[16][16], sZ[16][16], sB[16][16], sC[16][16];
    __shared__ u16 sY[16][16];
    const size_t base = (size_t)b*LSEQ + (size_t)s*128;
    for (int c0 = 0; c0 < 128; c0 += 16) {
        __syncthreads();
        {
            int tr = tid >> 4, tc = tid & 15;
            size_t row = base + c0 + tr;
            sD[tr][tc] = delta[row*DIN + d0+tc];
            sU[tr][tc] = u[row*DIN + d0+tc];
            sZ[tr][tc] = xz[row*2048 + DIN + d0+tc];
            sB[tr][tc] = xdbl[row*64 + DTRANK + tc];
            sC[tr][tc] = xdbl[row*64 + DTRANK + DSTATE + tc];
        }
        __syncthreads();
        #pragma unroll
        for (int t = 0; t < 16; ++t) {
            float dv = sD[t][dl], uv = sU[t][dl], Bv = sB[t][n], Cv = sC[t][n];
            float dA = __expf(dv * Adn);
            h = fmaf(dA, h, dv*uv*Bv);
            float p = red16(h * Cv);
            if (n == 0) {
                float zv = sZ[t][dl];
                sY[t][dl] = f2bf((p + uv*Dd) * (zv * sigmoidf_(zv)));
            }
        }
        __syncthreads();
        {
            int tr = tid >> 4, tc = tid & 15;
            yb[(base + c0 + tr)*DIN + d0 + tc] = sY[tr][tc];
        }
    }
    if (s == 7) {
        size_t row = (size_t)b*LSEQ + 1024;
        float dv = delta[row*DIN + d];
        float uv = u[row*DIN + d];
        float zv = xz[row*2048 + DIN + d];
        float Bv = xdbl[row*64 + DTRANK + n];
        float Cv = xdbl[row*64 + DTRANK + DSTATE + n];
        float dA = __expf(dv * Adn);
        h = fmaf(dA, h, dv*uv*Bv);
        float p = red16(h * Cv);
        if (n == 0)
            yb[row*DIN + d] = f2bf((p + uv*Dd) * (zv * sigmoidf_(zv)));
    }
}

// =============== softmax over sequence + weighted pool ===============
__global__ __launch_bounds__(256) void softpool(
    const float* __restrict__ a, const float* __restrict__ yh,
    float* __restrict__ pooled)
{
    int b  = blockIdx.y;
    int jj = threadIdx.x & 63;
    int j  = blockIdx.x * 64 + jj;
    int li = threadIdx.x >> 6;
    float m = -3.0e38f, s = 0.f, p = 0.f;
    for (int l = li; l < LSEQ; l += 4) {
        size_t off = ((size_t)(b*LSEQ + l))*OUTD + j;
        float av = a[off], yv = yh[off];
        float mn = fmaxf(m, av);
        float sc = __expf(m - mn);
        float e  = __expf(av - mn);
        s = s*sc + e;
        p = p*sc + yv*e;
        m = mn;
    }
    __shared__ float sm[4][64], ss[4][64], sp[4][64];
    sm[li][jj] = m; ss[li][jj] = s; sp[li][jj] = p;
    __syncthreads();
    if (li == 0) {
        #pragma unroll
        for (int k2 = 1; k2 < 4; ++k2) {
            float m2 = sm[k2][jj], s2 = ss[k2][jj], p2 = sp[k2][jj];
            float M2 = fmaxf(m, m2);
            float c1 = __expf(m - M2), c2 = __expf(m2 - M2);
            s = s*c1 + s2*c2;
            p = p*c1 + p2*c2;
            m = M2;
        }
        pooled[(size_t)b*OUTD + j] = p / s;
    }
}

extern "C" void kernel_launch(void* const* d_in, const int* in_sizes, int n_in,
                              void* d_out, int out_size, void* d_ws, size_t ws_size,
                              hipStream_t stream) {
    const float* img     = (const float*)d_in[0];
    const float* patch_W = (const float*)d_in[1];
    const float* patch_b = (const float*)d_in[2];
    const float* pos_emb = (const float*)d_in[3];
    const float* cls_tok = (const float*)d_in[4];
    const float* ln_w    = (const float*)d_in[5];
    const float* ln_b    = (const float*)d_in[6];
    const float* in_W    = (const float*)d_in[7];
    const float* conv_w  = (const float*)d_in[8];
    const float* conv_b  = (const float*)d_in[9];
    const float* xproj_W = (const float*)d_in[10];
    const float* dt_W    = (const float*)d_in[11];
    const float* dt_b    = (const float*)d_in[12];
    const float* A_log   = (const float*)d_in[13];
    const float* Dp      = (const float*)d_in[14];
    const float* out_W   = (const float*)d_in[15];
    const float* sl1_W   = (const float*)d_in[16];
    const float* sl1_b   = (const float*)d_in[17];
    const float* sl1_lnw = (const float*)d_in[18];
    const float* sl1_lnb = (const float*)d_in[19];
    const float* sl2_W   = (const float*)d_in[20];
    const float* sl2_b   = (const float*)d_in[21];
    const float* sl2_lnw = (const float*)d_in[22];
    const float* sl2_lnb = (const float*)d_in[23];
    const float* lat_lnw = (const float*)d_in[24];
    const float* lat_lnb = (const float*)d_in[25];
    float* out = (float*)d_out;
    float* ws  = (float*)d_ws;

    // ---- f32 workspace (floats) ----
    float* x     = ws + 0;          // 2,099,200
    float* xz    = ws + 2099200;    // 8,396,800  (head: yh @ +0, t2 @ +2,099,200)
    float* u     = ws + 10496000;   // 4,198,400  (head: a)
    float* xdbl  = ws + 14694400;   //   262,400  (head: pooled)
    float* delta = ws + 14956800;   // 4,198,400  (also: patch tmp / xproj partials / head t1)
    // ---- bf16 workspace (u16) ----
    u16* ub      = (u16*)(ws + 19155200);
    u16* regA    = ub + 0;          // 4,325,376 : img_bf / y_bf / yh_bf
    u16* regB    = ub + 4325376;    // 2,162,688 : xn_bf / scan segbufs / x_bf
    u16* xdbl_bf = ub + 6488064;    //   270,336
    u16* pWt     = ub + 6758400;
    u16* inWt    = ub + 7151616;
    u16* outWt   = ub + 9248768;
    u16* dtWt    = ub + 10297344;
    u16* s1t     = ub + 10362880;
    u16* s2t     = ub + 10625024;

    float* yh     = xz;
    float* t2     = xz + 2099200;
    float* a      = u;
    float* pooled = xdbl;
    float* t1     = delta;
    // scan segment buffers (in regB region, dead between in-proj and out-proj)
    float* segH   = (float*)regB;          // 4*8*16384 = 524,288 floats
    float* segA   = segH + 524288;         // 4*7*16384 = 458,752 floats
    // xproj split-K partials (in delta region, dead before dt GEMM)
    float* xprojP = delta;                 // 4*262,400 floats

    // 0) prep
    prep_kernel<<<7104, 256, 0, stream>>>(img, patch_W, in_W, out_W, dt_W, sl1_W, sl2_W,
                                          regA, pWt, inWt, outWt, dtWt, s1t, s2t);

    // 1) patch GEMM + assemble
    gemm_mfma<2><<<dim3(512/128, 4096/64), 256, 0, stream>>>(
        regA, PDIM, pWt, delta, DIM, 4096, DIM, PDIM, patch_b, nullptr, 0, nullptr);
    assemble_x<<<(MROWS*DIM)/256, 256, 0, stream>>>(delta, cls_tok, pos_emb, x);

    // 2) mamba blocks
    for (int i = 0; i < NBLK; ++i) {
        ln_act<<<MROWS, 256, 0, stream>>>(x, ln_w + i*DIM, ln_b + i*DIM,
                                          nullptr, regB, 0);
        gemm_mfma<4><<<dim3(2048/128, 33), 256, 0, stream>>>(
            regB, DIM, inWt + (size_t)i*1048576, xz, 2*DIN,
            MROWS, 2*DIN, DIM, nullptr, nullptr, 0, nullptr);
        conv_silu<<<(MROWS*DIN)/256, 256, 0, stream>>>(
            xz, conv_w + i*DIN*KCONV, conv_b + i*DIN, u);
        xproj_gemm<<<dim3(65, 4), 256, 0, stream>>>(
            u, xproj_W + (size_t)i*DIN*64, xprojP);
        xproj_reduce<<<1025, 256, 0, stream>>>(xprojP, xdbl, xdbl_bf);
        gemm_mfma<2><<<dim3(1024/128, 65), 256, 0, stream>>>(
            xdbl_bf, 64, dtWt + (size_t)i*32768, delta, DIN,
            MROWS, DIN, DTRANK, dt_b + i*DIN, nullptr, 1, nullptr);
        scan_phase1<<<dim3(64, 4, 7), 256, 0, stream>>>(
            delta, u, xdbl, A_log + (size_t)i*DIN*DSTATE, segA, segH);
        scan_mid<<<256, 256, 0, stream>>>(segH, segA);
        scan_phase2<<<dim3(64, 4, 8), 256, 0, stream>>>(
            delta, u, xdbl, xz, A_log + (size_t)i*DIN*DSTATE, Dp + i*DIN,
            segH, regA);
        gemm_mfma<2><<<dim3(512/128, 65), 256, 0, stream>>>(
            regA, DIN, outWt + (size_t)i*524288, x, DIM,
            MROWS, DIM, DIN, nullptr, x, 0, (i == NBLK-1) ? regB : nullptr);
    }

    // 3) head
    gemm_mfma<2><<<dim3(512/128, 65), 256, 0, stream>>>(
        regB, DIM, s1t, t1, OUTD, MROWS, OUTD, DIM, sl1_b, nullptr, 0, nullptr);
    ln_act<<<MROWS, 256, 0, stream>>>(t1, sl1_lnw, sl1_lnb, yh, regA, 2);
    gemm_mfma<2><<<dim3(512/128, 65), 256, 0, stream>>>(
        regA, OUTD, s2t, t2, OUTD, MROWS, OUTD, OUTD, sl2_b, nullptr, 0, nullptr);
    ln_act<<<MROWS, 256, 0, stream>>>(t2, sl2_lnw, sl2_lnb, a, nullptr, 2);
    softpool<<<dim3(OUTD/64, B_), 256, 0, stream>>>(a, yh, pooled);
    ln_act<<<B_, 256, 0, stream>>>(pooled, lat_lnw, lat_lnb, out, nullptr, 0);
}

// Round 5
// 632.562 us; speedup vs baseline: 2.4933x; 1.0913x over previous
//
#include <hip/hip_runtime.h>
#include <cstdint>
#include <cstddef>

#define B_     4
#define NPATCH 1024
#define LSEQ   1025
#define PDIM   768
#define DIM    512
#define OUTD   512
#define DIN    1024
#define DSTATE 16
#define DTRANK 32
#define KCONV  4
#define NBLK   2
#define MROWS  (B_*LSEQ)   // 4100
#define NSEG_SP 17         // softpool l-segments (16*64 + tail)

typedef unsigned short u16;
typedef __attribute__((ext_vector_type(8))) short bf16x8;
typedef __attribute__((ext_vector_type(4))) float f32x4;

__device__ __forceinline__ float sigmoidf_(float x){ return 1.f/(1.f+__expf(-x)); }
__device__ __forceinline__ float geluf_(float x){ return 0.5f*x*(1.f+erff(x*0.70710678118654752f)); }
__device__ __forceinline__ u16 f2bf(float x){
    uint32_t b = __float_as_uint(x);
    b += 0x7FFFu + ((b >> 16) & 1u);
    return (u16)(b >> 16);
}
template<int CTRL>
__device__ __forceinline__ float dppmov(float x){
    return __int_as_float(__builtin_amdgcn_update_dpp(0, __float_as_int(x), CTRL, 0xF, 0xF, true));
}
// sum across each 16-lane group
__device__ __forceinline__ float red16(float p){
    p += dppmov<0xB1>(p);   // quad_perm xor1
    p += dppmov<0x4E>(p);   // quad_perm xor2
    p += dppmov<0x141>(p);  // row_half_mirror
    p += dppmov<0x140>(p);  // row_mirror
    return p;
}
__device__ __forceinline__ void gload16(const void* g, void* l){
    __builtin_amdgcn_global_load_lds((const __attribute__((address_space(1))) void*)g,
                                     (__attribute__((address_space(3))) void*)l, 16, 0, 0);
}

// =============== bf16 MFMA NT GEMM: C[M,N]f32 = A[M,K]bf16 @ Wt[N,K]bf16^T ===============
// tile: BM = MF*32 rows x 128 cols, 4 waves (2m x 2n). act: 0=none, 1=softplus
template<int MF>
__global__ __launch_bounds__(256) void gemm_mfma(
    const u16* __restrict__ A, int lda,
    const u16* __restrict__ Wt,          // [N][K]
    float* __restrict__ C, int ldc,
    int M, int N, int K,
    const float* __restrict__ bias,
    const float* __restrict__ addsrc,
    int act, u16* __restrict__ bf16out)
{
    __shared__ u16 lsA[MF*32*32];        // [BM][32]
    __shared__ u16 lsB[128*32];          // [128][32]
    const int tid = threadIdx.x;
    const int wid = tid >> 6, lane = tid & 63;
    const int m0 = blockIdx.y * (MF*32), n0 = blockIdx.x * 128;
    const int wm = (wid>>1)*(MF*16), wn = (wid&1)*64;
    f32x4 acc[MF][4] = {};

    const char* Agp = (const char*)(A + (size_t)m0 * lda);
    const char* Bgp = (const char*)(Wt + (size_t)n0 * K);
    const int lrow = lane >> 2;
    const int lcb  = (lane & 3) * 16;

    for (int k0 = 0; k0 < K; k0 += 32) {
        {
            int ra = wid*(MF*8) + lrow;
            gload16(Agp + (size_t)ra*(lda*2) + k0*2 + lcb, &lsA[(wid*(MF*8))*32]);
            if constexpr (MF == 4) {
                gload16(Agp + (size_t)(ra+16)*(lda*2) + k0*2 + lcb, &lsA[(wid*(MF*8)+16)*32]);
            }
        }
        {
            int rb = wid*32 + lrow;
            gload16(Bgp + (size_t)rb*(K*2) + k0*2 + lcb, &lsB[(wid*32)*32]);
            gload16(Bgp + (size_t)(rb+16)*(K*2) + k0*2 + lcb, &lsB[(wid*32+16)*32]);
        }
        __syncthreads();
        bf16x8 af[MF], bfr[4];
        #pragma unroll
        for (int i = 0; i < MF; ++i)
            af[i] = *(const bf16x8*)&lsA[(wm + i*16 + (lane&15))*32 + (lane>>4)*8];
        #pragma unroll
        for (int j = 0; j < 4; ++j)
            bfr[j] = *(const bf16x8*)&lsB[(wn + j*16 + (lane&15))*32 + (lane>>4)*8];
        #pragma unroll
        for (int i = 0; i < MF; ++i)
            #pragma unroll
            for (int j = 0; j < 4; ++j)
                acc[i][j] = __builtin_amdgcn_mfma_f32_16x16x32_bf16(af[i], bfr[j], acc[i][j], 0, 0, 0);
        __syncthreads();
    }
    #pragma unroll
    for (int i = 0; i < MF; ++i) {
        #pragma unroll
        for (int j = 0; j < 4; ++j) {
            int col = n0 + wn + j*16 + (lane & 15);
            float bv = bias ? bias[col] : 0.f;
            #pragma unroll
            for (int r = 0; r < 4; ++r) {
                int row = m0 + wm + i*16 + (lane>>4)*4 + r;
                if (row < M) {
                    float v = acc[i][j][r] + bv;
                    if (addsrc) v += addsrc[(size_t)row*ldc + col];
                    if (act == 1) v = (v > 20.f) ? v : log1pf(__expf(v));
                    C[(size_t)row*ldc + col] = v;
                    if (bf16out) bf16out[(size_t)row*ldc + col] = f2bf(v);
                }
            }
        }
    }
}

// =============== xproj split-K f32 GEMM: P[kc][4100][64] partials ===============
__global__ __launch_bounds__(256) void xproj_gemm(
    const float* __restrict__ Au,      // [4100][1024]
    const float* __restrict__ W,       // [1024][64]
    float* __restrict__ P)
{
    __shared__ float As[16][68];
    __shared__ float Bs[16][68];
    int tid = threadIdx.x;
    int tx = tid & 15, ty = tid >> 4;
    int m0 = blockIdx.x * 64;
    int kbase = blockIdx.y * 256;
    float acc[4][4] = {};
    for (int k0 = kbase; k0 < kbase + 256; k0 += 16) {
        {
            int r  = tid >> 2;
            int kq = (tid & 3) << 2;
            float4 va = make_float4(0.f,0.f,0.f,0.f);
            int gr = m0 + r;
            if (gr < MROWS) va = *reinterpret_cast<const float4*>(Au + (size_t)gr*DIN + k0 + kq);
            As[kq+0][r]=va.x; As[kq+1][r]=va.y; As[kq+2][r]=va.z; As[kq+3][r]=va.w;
        }
        {
            int kk = tid >> 4;
            int nq = (tid & 15) << 2;
            float4 vb = *reinterpret_cast<const float4*>(W + (size_t)(k0+kk)*64 + nq);
            Bs[kk][nq+0]=vb.x; Bs[kk][nq+1]=vb.y; Bs[kk][nq+2]=vb.z; Bs[kk][nq+3]=vb.w;
        }
        __syncthreads();
        #pragma unroll
        for (int k = 0; k < 16; ++k) {
            float a0=As[k][ty*4+0],a1=As[k][ty*4+1],a2=As[k][ty*4+2],a3=As[k][ty*4+3];
            float b0=Bs[k][tx*4+0],b1=Bs[k][tx*4+1],b2=Bs[k][tx*4+2],b3=Bs[k][tx*4+3];
            acc[0][0]=fmaf(a0,b0,acc[0][0]); acc[0][1]=fmaf(a0,b1,acc[0][1]);
            acc[0][2]=fmaf(a0,b2,acc[0][2]); acc[0][3]=fmaf(a0,b3,acc[0][3]);
            acc[1][0]=fmaf(a1,b0,acc[1][0]); acc[1][1]=fmaf(a1,b1,acc[1][1]);
            acc[1][2]=fmaf(a1,b2,acc[1][2]); acc[1][3]=fmaf(a1,b3,acc[1][3]);
            acc[2][0]=fmaf(a2,b0,acc[2][0]); acc[2][1]=fmaf(a2,b1,acc[2][1]);
            acc[2][2]=fmaf(a2,b2,acc[2][2]); acc[2][3]=fmaf(a2,b3,acc[2][3]);
            acc[3][0]=fmaf(a3,b0,acc[3][0]); acc[3][1]=fmaf(a3,b1,acc[3][1]);
            acc[3][2]=fmaf(a3,b2,acc[3][2]); acc[3][3]=fmaf(a3,b3,acc[3][3]);
        }
        __syncthreads();
    }
    float* Pp = P + (size_t)blockIdx.y * (MROWS*64);
    #pragma unroll
    for (int i = 0; i < 4; ++i) {
        int r = m0 + ty*4 + i;
        if (r >= MROWS) continue;
        #pragma unroll
        for (int j = 0; j < 4; ++j)
            Pp[(size_t)r*64 + tx*4 + j] = acc[i][j];
    }
}

__global__ __launch_bounds__(256) void xproj_reduce(
    const float* __restrict__ P, float* __restrict__ xdbl, u16* __restrict__ xdbl_bf)
{
    int idx = blockIdx.x*256 + threadIdx.x;      // 262400 total
    float v = P[idx] + P[MROWS*64 + idx] + P[2*MROWS*64 + idx] + P[3*MROWS*64 + idx];
    xdbl[idx] = v;
    xdbl_bf[idx] = f2bf(v);
}

// =============== prep: img cast + weight transpose-casts ===============
__device__ void tcast(const float* __restrict__ in, u16* __restrict__ outp,
                      int K, int N, int tix)
{
    __shared__ float tl[32][33];
    int ntn = N >> 5;
    int tk = tix / ntn, tn = tix - tk*ntn;
    int tid = threadIdx.x;
    int r = tid >> 3, c0 = (tid & 7) << 2;
    float4 v = *(const float4*)&in[(size_t)(tk*32 + r)*N + tn*32 + c0];
    tl[r][c0+0]=v.x; tl[r][c0+1]=v.y; tl[r][c0+2]=v.z; tl[r][c0+3]=v.w;
    __syncthreads();
    int nn = r, k0 = c0;
    uint32_t w0 = f2bf(tl[k0+0][nn]) | ((uint32_t)f2bf(tl[k0+1][nn]) << 16);
    uint32_t w1 = f2bf(tl[k0+2][nn]) | ((uint32_t)f2bf(tl[k0+3][nn]) << 16);
    uint2 o; o.x = w0; o.y = w1;
    *(uint2*)&outp[(size_t)(tn*32 + nn)*K + tk*32 + k0] = o;
}

__global__ __launch_bounds__(256) void prep_kernel(
    const float* __restrict__ img, const float* __restrict__ pW,
    const float* __restrict__ inW, const float* __restrict__ outW,
    const float* __restrict__ dtW, const float* __restrict__ s1W,
    const float* __restrict__ s2W,
    u16* imgb, u16* pWt, u16* inWt, u16* outWt, u16* dtWt, u16* s1t, u16* s2t)
{
    int b = blockIdx.x;
    if (b < 3072) {
        int idx = b*1024 + threadIdx.x*4;
        float4 v = *(const float4*)&img[idx];
        uint2 o;
        o.x = f2bf(v.x) | ((uint32_t)f2bf(v.y) << 16);
        o.y = f2bf(v.z) | ((uint32_t)f2bf(v.w) << 16);
        *(uint2*)&imgb[idx] = o;
        return;
    }
    b -= 3072;
    if (b < 384)  { tcast(pW, pWt, 768, 512, b); return; }
    b -= 384;
    if (b < 2048) { int blk=b>>10, t=b&1023; tcast(inW + (size_t)blk*512*2048, inWt + (size_t)blk*1048576, 512, 2048, t); return; }
    b -= 2048;
    if (b < 1024) { int blk=b>>9, t=b&511; tcast(outW + (size_t)blk*1024*512, outWt + (size_t)blk*524288, 1024, 512, t); return; }
    b -= 1024;
    if (b < 64)   { int blk=b>>5, t=b&31; tcast(dtW + (size_t)blk*32*1024, dtWt + (size_t)blk*32768, 32, 1024, t); return; }
    b -= 64;
    if (b < 256)  { tcast(s1W, s1t, 512, 512, b); return; }
    b -= 256;
    tcast(s2W, s2t, 512, 512, b);
}

// =============== assemble x = concat(cls, patches) + pos ===============
__global__ __launch_bounds__(256) void assemble_x(
    const float* __restrict__ tmp, const float* __restrict__ cls,
    const float* __restrict__ pos, float* __restrict__ x)
{
    int idx = blockIdx.x*256 + threadIdx.x;
    int d = idx & 511;
    int r = idx >> 9;
    int l = r % LSEQ;
    int b = r / LSEQ;
    float v = (l == 0) ? cls[d] : tmp[((size_t)(b*NPATCH + l-1))*DIM + d];
    x[idx] = v + pos[(size_t)l*DIM + d];
}

// =============== row LayerNorm (+gelu), 512 cols, dual f32/bf16 outputs ===============
__global__ __launch_bounds__(256) void ln_act(
    const float* __restrict__ in, const float* __restrict__ gw, const float* __restrict__ gb,
    float* __restrict__ f32out, u16* __restrict__ bf16out, int act)
{
    int row = blockIdx.x;
    const float* p = in + (size_t)row * 512;
    int t = threadIdx.x;
    float v0 = p[t], v1 = p[t + 256];
    float s = v0 + v1, q = v0*v0 + v1*v1;
    #pragma unroll
    for (int o = 32; o; o >>= 1) { s += __shfl_xor(s, o); q += __shfl_xor(q, o); }
    __shared__ float ls[4], lq[4];
    int w = t >> 6;
    if ((t & 63) == 0) { ls[w] = s; lq[w] = q; }
    __syncthreads();
    s = ls[0]+ls[1]+ls[2]+ls[3];
    q = lq[0]+lq[1]+lq[2]+lq[3];
    float mean = s * (1.f/512.f);
    float var  = q * (1.f/512.f) - mean*mean;
    float inv  = rsqrtf(var + 1e-5f);
    float o0 = (v0-mean)*inv*gw[t]     + gb[t];
    float o1 = (v1-mean)*inv*gw[t+256] + gb[t+256];
    if (act == 2) { o0 = geluf_(o0); o1 = geluf_(o1); }
    if (f32out)  { f32out[(size_t)row*512 + t] = o0; f32out[(size_t)row*512 + t + 256] = o1; }
    if (bf16out) { bf16out[(size_t)row*512 + t] = f2bf(o0); bf16out[(size_t)row*512 + t + 256] = f2bf(o1); }
}

// =============== causal depthwise conv (K=4) + SiLU, float4 per thread ===============
__global__ __launch_bounds__(256) void conv_silu(
    const float* __restrict__ xz, const float* __restrict__ cw,
    const float* __restrict__ cb, float* __restrict__ uo)
{
    int idx = blockIdx.x*256 + threadIdx.x;   // 4100*256 total
    int dq = idx & 255;
    int r  = idx >> 8;
    int b = r / LSEQ, l = r - b*LSEQ;
    int d0 = dq << 2;
    float4 w0 = *(const float4*)&cw[(d0+0)*4];
    float4 w1 = *(const float4*)&cw[(d0+1)*4];
    float4 w2 = *(const float4*)&cw[(d0+2)*4];
    float4 w3 = *(const float4*)&cw[(d0+3)*4];
    float4 acc = *(const float4*)&cb[d0];
    const float* wv0 = &w0.x; const float* wv1 = &w1.x;
    const float* wv2 = &w2.x; const float* wv3 = &w3.x;
    #pragma unroll
    for (int k = 0; k < KCONV; ++k) {
        int ls = l - (KCONV-1) + k;
        if (ls >= 0) {
            float4 v = *(const float4*)&xz[((size_t)(b*LSEQ + ls))*2048 + d0];
            acc.x = fmaf(wv0[k], v.x, acc.x);
            acc.y = fmaf(wv1[k], v.y, acc.y);
            acc.z = fmaf(wv2[k], v.z, acc.z);
            acc.w = fmaf(wv3[k], v.w, acc.w);
        }
    }
    acc.x *= sigmoidf_(acc.x);
    acc.y *= sigmoidf_(acc.y);
    acc.z *= sigmoidf_(acc.z);
    acc.w *= sigmoidf_(acc.w);
    *(float4*)&uo[(size_t)r*DIN + d0] = acc;
}

// =============== segmented selective scan ===============
__global__ __launch_bounds__(256) void scan_phase1(
    const float* __restrict__ delta, const float* __restrict__ u,
    const float* __restrict__ xdbl,  const float* __restrict__ A_log,
    float* __restrict__ Aseg, float* __restrict__ Hseg)
{
    const int dg = blockIdx.x, b = blockIdx.y, s = blockIdx.z;
    const int tid = threadIdx.x;
    const int n = tid & 15, dl = tid >> 4;
    const int d0 = dg*16, d = d0 + dl;
    const float Adn = -__expf(A_log[(size_t)d*DSTATE + n]);
    float ap = 1.f, h = 0.f;
    __shared__ float sD[16][16], sU[16][16], sB[16][16];
    const size_t base = (size_t)b*LSEQ + (size_t)s*128;
    for (int c0 = 0; c0 < 128; c0 += 16) {
        __syncthreads();
        {
            int tr = tid >> 4, tc = tid & 15;
            size_t row = base + c0 + tr;
            sD[tr][tc] = delta[row*DIN + d0+tc];
            sU[tr][tc] = u[row*DIN + d0+tc];
            sB[tr][tc] = xdbl[row*64 + DTRANK + tc];
        }
        __syncthreads();
        #pragma unroll
        for (int t = 0; t < 16; ++t) {
            float dv = sD[t][dl], uv = sU[t][dl], Bv = sB[t][n];
            float dA = __expf(dv * Adn);
            ap *= dA;
            h = fmaf(dA, h, dv*uv*Bv);
        }
    }
    int dn = d*DSTATE + n;
    Aseg[((size_t)b*7 + s)*16384 + dn] = ap;
    Hseg[((size_t)b*8 + s)*16384 + dn] = h;
}

__global__ __launch_bounds__(256) void scan_mid(
    float* __restrict__ Hseg, const float* __restrict__ Aseg)
{
    int idx = blockIdx.x*256 + threadIdx.x;      // 65536
    int b = idx >> 14, dn = idx & 16383;
    float prev = 0.f;
    #pragma unroll
    for (int s = 0; s < 7; ++s) {
        size_t offH = ((size_t)b*8 + s)*16384 + dn;
        float a  = Aseg[((size_t)b*7 + s)*16384 + dn];
        float hs = Hseg[offH];
        Hseg[offH] = prev;
        prev = fmaf(a, prev, hs);
    }
    Hseg[((size_t)b*8 + 7)*16384 + dn] = prev;
}

__global__ __launch_bounds__(256) void scan_phase2(
    const float* __restrict__ delta, const float* __restrict__ u,
    const float* __restrict__ xdbl,  const float* __restrict__ xz,
    const float* __restrict__ A_log, const float* __restrict__ Dp,
    const float* __restrict__ H0, u16* __restrict__ yb)
{
    const int dg = blockIdx.x, b = blockIdx.y, s = blockIdx.z;
    const int tid = threadIdx.x;
    const int n = tid & 15, dl = tid >> 4;
    const int d0 = dg*16, d = d0 + dl;
    const float Adn = -__expf(A_log[(size_t)d*DSTATE + n]);
    const float Dd = Dp[d];
    float h = H0[((size_t)b*8 + s)*16384 + d*DSTATE + n];
    __shared__ float sD[16][16], sU[16][16], sZ[16][16], sB[16][16], sC[16][16];
    __shared__ u16 sY[16][16];
    const size_t base = (size_t)b*LSEQ + (size_t)s*128;
    for (int c0 = 0; c0 < 128; c0 += 16) {
        __syncthreads();
        {
            int tr = tid >> 4, tc = tid & 15;
            size_t row = base + c0 + tr;
            sD[tr][tc] = delta[row*DIN + d0+tc];
            sU[tr][tc] = u[row*DIN + d0+tc];
            sZ[tr][tc] = xz[row*2048 + DIN + d0+tc];
            sB[tr][tc] = xdbl[row*64 + DTRANK + tc];
            sC[tr][tc] = xdbl[row*64 + DTRANK + DSTATE + tc];
        }
        __syncthreads();
        #pragma unroll
        for (int t = 0; t < 16; ++t) {
            float dv = sD[t][dl], uv = sU[t][dl], Bv = sB[t][n], Cv = sC[t][n];
            float dA = __expf(dv * Adn);
            h = fmaf(dA, h, dv*uv*Bv);
            float p = red16(h * Cv);
            if (n == 0) {
                float zv = sZ[t][dl];
                sY[t][dl] = f2bf((p + uv*Dd) * (zv * sigmoidf_(zv)));
            }
        }
        __syncthreads();
        {
            int tr = tid >> 4, tc = tid & 15;
            yb[(base + c0 + tr)*DIN + d0 + tc] = sY[tr][tc];
        }
    }
    if (s == 7) {
        size_t row = (size_t)b*LSEQ + 1024;
        float dv = delta[row*DIN + d];
        float uv = u[row*DIN + d];
        float zv = xz[row*2048 + DIN + d];
        float Bv = xdbl[row*64 + DTRANK + n];
        float Cv = xdbl[row*64 + DTRANK + DSTATE + n];
        float dA = __expf(dv * Adn);
        h = fmaf(dA, h, dv*uv*Bv);
        float p = red16(h * Cv);
        if (n == 0)
            yb[row*DIN + d] = f2bf((p + uv*Dd) * (zv * sigmoidf_(zv)));
    }
}

// =============== softmax-pool: phase 1 (per-segment partials) ===============
// grid (8 jb, 4 b, 17 seg), block 256 = 4 l-lanes x 64 j
__global__ __launch_bounds__(256) void softpool_seg(
    const float* __restrict__ a, const float* __restrict__ yh,
    float* __restrict__ pm, float* __restrict__ ps, float* __restrict__ pp)
{
    int b   = blockIdx.y;
    int seg = blockIdx.z;
    int jj = threadIdx.x & 63;
    int j  = blockIdx.x * 64 + jj;
    int li = threadIdx.x >> 6;
    int lbeg = seg * 64;
    int lend = min(lbeg + 64, LSEQ);
    float m = -3.0e38f, s = 0.f, p = 0.f;
    for (int l = lbeg + li; l < lend; l += 4) {
        size_t off = ((size_t)(b*LSEQ + l))*OUTD + j;
        float av = a[off], yv = yh[off];
        float mn = fmaxf(m, av);
        float sc = __expf(m - mn);
        float e  = __expf(av - mn);
        s = s*sc + e;
        p = p*sc + yv*e;
        m = mn;
    }
    __shared__ float sm[4][64], ss[4][64], sp[4][64];
    sm[li][jj] = m; ss[li][jj] = s; sp[li][jj] = p;
    __syncthreads();
    if (li == 0) {
        #pragma unroll
        for (int k2 = 1; k2 < 4; ++k2) {
            float m2 = sm[k2][jj], s2 = ss[k2][jj], p2 = sp[k2][jj];
            float M2 = fmaxf(m, m2);
            float c1 = __expf(m - M2), c2 = __expf(m2 - M2);
            s = s*c1 + s2*c2;
            p = p*c1 + p2*c2;
            m = M2;
        }
        int o = ((seg*B_ + b)*OUTD) + j;
        pm[o] = m; ps[o] = s; pp[o] = p;
    }
}

// =============== softmax-pool: phase 2 (combine 17 segments) ===============
__global__ __launch_bounds__(256) void softpool_combine(
    const float* __restrict__ pm, const float* __restrict__ ps,
    const float* __restrict__ pp, float* __restrict__ pooled)
{
    int idx = blockIdx.x*256 + threadIdx.x;   // 2048 total
    int b = idx >> 9, j = idx & 511;
    float m = -3.0e38f, s = 0.f, p = 0.f;
    #pragma unroll
    for (int seg = 0; seg < NSEG_SP; ++seg) {
        int o = ((seg*B_ + b)*OUTD) + j;
        float m2 = pm[o], s2 = ps[o], p2 = pp[o];
        float M2 = fmaxf(m, m2);
        float c1 = __expf(m - M2), c2 = __expf(m2 - M2);
        s = s*c1 + s2*c2;
        p = p*c1 + p2*c2;
        m = M2;
    }
    pooled[(size_t)b*OUTD + j] = p / s;
}

extern "C" void kernel_launch(void* const* d_in, const int* in_sizes, int n_in,
                              void* d_out, int out_size, void* d_ws, size_t ws_size,
                              hipStream_t stream) {
    const float* img     = (const float*)d_in[0];
    const float* patch_W = (const float*)d_in[1];
    const float* patch_b = (const float*)d_in[2];
    const float* pos_emb = (const float*)d_in[3];
    const float* cls_tok = (const float*)d_in[4];
    const float* ln_w    = (const float*)d_in[5];
    const float* ln_b    = (const float*)d_in[6];
    const float* in_W    = (const float*)d_in[7];
    const float* conv_w  = (const float*)d_in[8];
    const float* conv_b  = (const float*)d_in[9];
    const float* xproj_W = (const float*)d_in[10];
    const float* dt_W    = (const float*)d_in[11];
    const float* dt_b    = (const float*)d_in[12];
    const float* A_log   = (const float*)d_in[13];
    const float* Dp      = (const float*)d_in[14];
    const float* out_W   = (const float*)d_in[15];
    const float* sl1_W   = (const float*)d_in[16];
    const float* sl1_b   = (const float*)d_in[17];
    const float* sl1_lnw = (const float*)d_in[18];
    const float* sl1_lnb = (const float*)d_in[19];
    const float* sl2_W   = (const float*)d_in[20];
    const float* sl2_b   = (const float*)d_in[21];
    const float* sl2_lnw = (const float*)d_in[22];
    const float* sl2_lnb = (const float*)d_in[23];
    const float* lat_lnw = (const float*)d_in[24];
    const float* lat_lnb = (const float*)d_in[25];
    float* out = (float*)d_out;
    float* ws  = (float*)d_ws;

    // ---- f32 workspace (floats) ----
    float* x     = ws + 0;          // 2,099,200
    float* xz    = ws + 2099200;    // 8,396,800  (head: yh @ +0, t2 @ +2,099,200)
    float* u     = ws + 10496000;   // 4,198,400  (head: a)
    float* xdbl  = ws + 14694400;   //   262,400  (head: pooled + softpool partials)
    float* delta = ws + 14956800;   // 4,198,400  (patch tmp / xproj partials / head t1)
    // ---- bf16 workspace (u16) ----
    u16* ub      = (u16*)(ws + 19155200);
    u16* regA    = ub + 0;          // img_bf / y_bf / yh_bf
    u16* regB    = ub + 4325376;    // xn_bf / scan segbufs / x_bf
    u16* xdbl_bf = ub + 6488064;
    u16* pWt     = ub + 6758400;
    u16* inWt    = ub + 7151616;
    u16* outWt   = ub + 9248768;
    u16* dtWt    = ub + 10297344;
    u16* s1t     = ub + 10362880;
    u16* s2t     = ub + 10625024;

    float* yh     = xz;
    float* t2     = xz + 2099200;
    float* a      = u;
    float* pooled = xdbl;
    float* spm    = xdbl + 8192;              // 17*4*512 = 34,816
    float* sps    = spm + 34816;
    float* spp    = sps + 34816;              // ends at +112,640 < 262,400
    float* t1     = delta;
    float* segH   = (float*)regB;
    float* segA   = segH + 524288;
    float* xprojP = delta;

    // 0) prep
    prep_kernel<<<7104, 256, 0, stream>>>(img, patch_W, in_W, out_W, dt_W, sl1_W, sl2_W,
                                          regA, pWt, inWt, outWt, dtWt, s1t, s2t);

    // 1) patch GEMM + assemble
    gemm_mfma<2><<<dim3(512/128, 4096/64), 256, 0, stream>>>(
        regA, PDIM, pWt, delta, DIM, 4096, DIM, PDIM, patch_b, nullptr, 0, nullptr);
    assemble_x<<<(MROWS*DIM)/256, 256, 0, stream>>>(delta, cls_tok, pos_emb, x);

    // 2) mamba blocks
    for (int i = 0; i < NBLK; ++i) {
        ln_act<<<MROWS, 256, 0, stream>>>(x, ln_w + i*DIM, ln_b + i*DIM,
                                          nullptr, regB, 0);
        gemm_mfma<4><<<dim3(2048/128, 33), 256, 0, stream>>>(
            regB, DIM, inWt + (size_t)i*1048576, xz, 2*DIN,
            MROWS, 2*DIN, DIM, nullptr, nullptr, 0, nullptr);
        conv_silu<<<MROWS, 256, 0, stream>>>(
            xz, conv_w + i*DIN*KCONV, conv_b + i*DIN, u);
        xproj_gemm<<<dim3(65, 4), 256, 0, stream>>>(
            u, xproj_W + (size_t)i*DIN*64, xprojP);
        xproj_reduce<<<1025, 256, 0, stream>>>(xprojP, xdbl, xdbl_bf);
        gemm_mfma<2><<<dim3(1024/128, 65), 256, 0, stream>>>(
            xdbl_bf, 64, dtWt + (size_t)i*32768, delta, DIN,
            MROWS, DIN, DTRANK, dt_b + i*DIN, nullptr, 1, nullptr);
        scan_phase1<<<dim3(64, 4, 7), 256, 0, stream>>>(
            delta, u, xdbl, A_log + (size_t)i*DIN*DSTATE, segA, segH);
        scan_mid<<<256, 256, 0, stream>>>(segH, segA);
        scan_phase2<<<dim3(64, 4, 8), 256, 0, stream>>>(
            delta, u, xdbl, xz, A_log + (size_t)i*DIN*DSTATE, Dp + i*DIN,
            segH, regA);
        gemm_mfma<2><<<dim3(512/128, 65), 256, 0, stream>>>(
            regA, DIN, outWt + (size_t)i*524288, x, DIM,
            MROWS, DIM, DIN, nullptr, x, 0, (i == NBLK-1) ? regB : nullptr);
    }

    // 3) head
    gemm_mfma<2><<<dim3(512/128, 65), 256, 0, stream>>>(
        regB, DIM, s1t, t1, OUTD, MROWS, OUTD, DIM, sl1_b, nullptr, 0, nullptr);
    ln_act<<<MROWS, 256, 0, stream>>>(t1, sl1_lnw, sl1_lnb, yh, regA, 2);
    gemm_mfma<2><<<dim3(512/128, 65), 256, 0, stream>>>(
        regA, OUTD, s2t, t2, OUTD, MROWS, OUTD, OUTD, sl2_b, nullptr, 0, nullptr);
    ln_act<<<MROWS, 256, 0, stream>>>(t2, sl2_lnw, sl2_lnb, a, nullptr, 2);
    softpool_seg<<<dim3(OUTD/64, B_, NSEG_SP), 256, 0, stream>>>(a, yh, spm, sps, spp);
    softpool_combine<<<8, 256, 0, stream>>>(spm, sps, spp, pooled);
    ln_act<<<B_, 256, 0, stream>>>(pooled, lat_lnw, lat_lnb, out, nullptr, 0);
}

// Round 6
// 632.112 us; speedup vs baseline: 2.4951x; 1.0007x over previous
//
#include <hip/hip_runtime.h>
#include <cstdint>
#include <cstddef>

#define B_     4
#define NPATCH 1024
#define LSEQ   1025
#define PDIM   768
#define DIM    512
#define OUTD   512
#define DIN    1024
#define DSTATE 16
#define DTRANK 32
#define KCONV  4
#define NBLK   2
#define MROWS  (B_*LSEQ)   // 4100
#define NSEG_SP 17         // softpool l-segments

typedef unsigned short u16;
typedef __attribute__((ext_vector_type(8))) short bf16x8;
typedef __attribute__((ext_vector_type(4))) float f32x4;

__device__ __forceinline__ float sigmoidf_(float x){ return 1.f/(1.f+__expf(-x)); }
__device__ __forceinline__ float geluf_(float x){ return 0.5f*x*(1.f+erff(x*0.70710678118654752f)); }
__device__ __forceinline__ u16 f2bf(float x){
    uint32_t b = __float_as_uint(x);
    b += 0x7FFFu + ((b >> 16) & 1u);
    return (u16)(b >> 16);
}
template<int CTRL>
__device__ __forceinline__ float dppmov(float x){
    return __int_as_float(__builtin_amdgcn_update_dpp(0, __float_as_int(x), CTRL, 0xF, 0xF, true));
}
// sum across each 16-lane group
__device__ __forceinline__ float red16(float p){
    p += dppmov<0xB1>(p);   // quad_perm xor1
    p += dppmov<0x4E>(p);   // quad_perm xor2
    p += dppmov<0x141>(p);  // row_half_mirror
    p += dppmov<0x140>(p);  // row_mirror
    return p;
}
__device__ __forceinline__ void gload16(const void* g, void* l){
    __builtin_amdgcn_global_load_lds((const __attribute__((address_space(1))) void*)g,
                                     (__attribute__((address_space(3))) void*)l, 16, 0, 0);
}

// =============== bf16 MFMA NT GEMM: C[M,N]f32 = A[M,K]bf16 @ Wt[N,K]bf16^T ===============
// tile: BM = MF*32 rows x 128 cols, 4 waves (2m x 2n). act: 0=none, 1=softplus
// LDS tiles are XOR-swizzled (both-sides): physical 16B-slot = logical ^ ((row>>1)&3).
// Staging realizes this by pre-swizzling the GLOBAL source column (rule 21).
template<int MF>
__global__ __launch_bounds__(256) void gemm_mfma(
    const u16* __restrict__ A, int lda,
    const u16* __restrict__ Wt,          // [N][K]
    float* __restrict__ C, int ldc,
    int M, int N, int K,
    const float* __restrict__ bias,
    const float* __restrict__ addsrc,
    int act, u16* __restrict__ bf16out)
{
    __shared__ u16 lsA[MF*32*32];        // [BM][32]
    __shared__ u16 lsB[128*32];          // [128][32]
    const int tid = threadIdx.x;
    const int wid = tid >> 6, lane = tid & 63;
    const int m0 = blockIdx.y * (MF*32), n0 = blockIdx.x * 128;
    const int wm = (wid>>1)*(MF*16), wn = (wid&1)*64;
    f32x4 acc[MF][4] = {};

    const char* Agp = (const char*)(A + (size_t)m0 * lda);
    const char* Bgp = (const char*)(Wt + (size_t)n0 * K);
    const int lrow = lane >> 2;
    // staging: pre-swizzled global 16B-column for this lane
    const int lcb  = (((lane & 3) ^ ((lane >> 3) & 3))) * 16;
    // reading: physical slot for fragment reads
    const int rsw  = ((lane & 15) >> 1) & 3;
    const int acol = ((lane >> 4) ^ rsw) * 8;    // u16 offset within row

    for (int k0 = 0; k0 < K; k0 += 32) {
        {
            int ra = wid*(MF*8) + lrow;
            gload16(Agp + (size_t)ra*(lda*2) + k0*2 + lcb, &lsA[(wid*(MF*8))*32]);
            if constexpr (MF == 4) {
                gload16(Agp + (size_t)(ra+16)*(lda*2) + k0*2 + lcb, &lsA[(wid*(MF*8)+16)*32]);
            }
        }
        {
            int rb = wid*32 + lrow;
            gload16(Bgp + (size_t)rb*(K*2) + k0*2 + lcb, &lsB[(wid*32)*32]);
            gload16(Bgp + (size_t)(rb+16)*(K*2) + k0*2 + lcb, &lsB[(wid*32+16)*32]);
        }
        __syncthreads();
        bf16x8 af[MF], bfr[4];
        #pragma unroll
        for (int i = 0; i < MF; ++i)
            af[i] = *(const bf16x8*)&lsA[(wm + i*16 + (lane&15))*32 + acol];
        #pragma unroll
        for (int j = 0; j < 4; ++j)
            bfr[j] = *(const bf16x8*)&lsB[(wn + j*16 + (lane&15))*32 + acol];
        #pragma unroll
        for (int i = 0; i < MF; ++i)
            #pragma unroll
            for (int j = 0; j < 4; ++j)
                acc[i][j] = __builtin_amdgcn_mfma_f32_16x16x32_bf16(af[i], bfr[j], acc[i][j], 0, 0, 0);
        __syncthreads();
    }
    #pragma unroll
    for (int i = 0; i < MF; ++i) {
        #pragma unroll
        for (int j = 0; j < 4; ++j) {
            int col = n0 + wn + j*16 + (lane & 15);
            float bv = bias ? bias[col] : 0.f;
            #pragma unroll
            for (int r = 0; r < 4; ++r) {
                int row = m0 + wm + i*16 + (lane>>4)*4 + r;
                if (row < M) {
                    float v = acc[i][j][r] + bv;
                    if (addsrc) v += addsrc[(size_t)row*ldc + col];
                    if (act == 1) v = (v > 20.f) ? v : log1pf(__expf(v));
                    C[(size_t)row*ldc + col] = v;
                    if (bf16out) bf16out[(size_t)row*ldc + col] = f2bf(v);
                }
            }
        }
    }
}

// =============== xproj split-K f32 GEMM: P[kc][4100][64] partials ===============
__global__ __launch_bounds__(256) void xproj_gemm(
    const float* __restrict__ Au,      // [4100][1024]
    const float* __restrict__ W,       // [1024][64]
    float* __restrict__ P)
{
    __shared__ float As[16][68];
    __shared__ float Bs[16][68];
    int tid = threadIdx.x;
    int tx = tid & 15, ty = tid >> 4;
    int m0 = blockIdx.x * 64;
    int kbase = blockIdx.y * 256;
    float acc[4][4] = {};
    for (int k0 = kbase; k0 < kbase + 256; k0 += 16) {
        {
            int r  = tid >> 2;
            int kq = (tid & 3) << 2;
            float4 va = make_float4(0.f,0.f,0.f,0.f);
            int gr = m0 + r;
            if (gr < MROWS) va = *reinterpret_cast<const float4*>(Au + (size_t)gr*DIN + k0 + kq);
            As[kq+0][r]=va.x; As[kq+1][r]=va.y; As[kq+2][r]=va.z; As[kq+3][r]=va.w;
        }
        {
            int kk = tid >> 4;
            int nq = (tid & 15) << 2;
            float4 vb = *reinterpret_cast<const float4*>(W + (size_t)(k0+kk)*64 + nq);
            Bs[kk][nq+0]=vb.x; Bs[kk][nq+1]=vb.y; Bs[kk][nq+2]=vb.z; Bs[kk][nq+3]=vb.w;
        }
        __syncthreads();
        #pragma unroll
        for (int k = 0; k < 16; ++k) {
            float a0=As[k][ty*4+0],a1=As[k][ty*4+1],a2=As[k][ty*4+2],a3=As[k][ty*4+3];
            float b0=Bs[k][tx*4+0],b1=Bs[k][tx*4+1],b2=Bs[k][tx*4+2],b3=Bs[k][tx*4+3];
            acc[0][0]=fmaf(a0,b0,acc[0][0]); acc[0][1]=fmaf(a0,b1,acc[0][1]);
            acc[0][2]=fmaf(a0,b2,acc[0][2]); acc[0][3]=fmaf(a0,b3,acc[0][3]);
            acc[1][0]=fmaf(a1,b0,acc[1][0]); acc[1][1]=fmaf(a1,b1,acc[1][1]);
            acc[1][2]=fmaf(a1,b2,acc[1][2]); acc[1][3]=fmaf(a1,b3,acc[1][3]);
            acc[2][0]=fmaf(a2,b0,acc[2][0]); acc[2][1]=fmaf(a2,b1,acc[2][1]);
            acc[2][2]=fmaf(a2,b2,acc[2][2]); acc[2][3]=fmaf(a2,b3,acc[2][3]);
            acc[3][0]=fmaf(a3,b0,acc[3][0]); acc[3][1]=fmaf(a3,b1,acc[3][1]);
            acc[3][2]=fmaf(a3,b2,acc[3][2]); acc[3][3]=fmaf(a3,b3,acc[3][3]);
        }
        __syncthreads();
    }
    float* Pp = P + (size_t)blockIdx.y * (MROWS*64);
    #pragma unroll
    for (int i = 0; i < 4; ++i) {
        int r = m0 + ty*4 + i;
        if (r >= MROWS) continue;
        #pragma unroll
        for (int j = 0; j < 4; ++j)
            Pp[(size_t)r*64 + tx*4 + j] = acc[i][j];
    }
}

__global__ __launch_bounds__(256) void xproj_reduce(
    const float* __restrict__ P, float* __restrict__ xdbl, u16* __restrict__ xdbl_bf)
{
    int idx = blockIdx.x*256 + threadIdx.x;      // 262400 total
    float v = P[idx] + P[MROWS*64 + idx] + P[2*MROWS*64 + idx] + P[3*MROWS*64 + idx];
    xdbl[idx] = v;
    xdbl_bf[idx] = f2bf(v);
}

// =============== prep: img cast + weight transpose-casts ===============
__device__ void tcast(const float* __restrict__ in, u16* __restrict__ outp,
                      int K, int N, int tix)
{
    __shared__ float tl[32][33];
    int ntn = N >> 5;
    int tk = tix / ntn, tn = tix - tk*ntn;
    int tid = threadIdx.x;
    int r = tid >> 3, c0 = (tid & 7) << 2;
    float4 v = *(const float4*)&in[(size_t)(tk*32 + r)*N + tn*32 + c0];
    tl[r][c0+0]=v.x; tl[r][c0+1]=v.y; tl[r][c0+2]=v.z; tl[r][c0+3]=v.w;
    __syncthreads();
    int nn = r, k0 = c0;
    uint32_t w0 = f2bf(tl[k0+0][nn]) | ((uint32_t)f2bf(tl[k0+1][nn]) << 16);
    uint32_t w1 = f2bf(tl[k0+2][nn]) | ((uint32_t)f2bf(tl[k0+3][nn]) << 16);
    uint2 o; o.x = w0; o.y = w1;
    *(uint2*)&outp[(size_t)(tn*32 + nn)*K + tk*32 + k0] = o;
}

__global__ __launch_bounds__(256) void prep_kernel(
    const float* __restrict__ img, const float* __restrict__ pW,
    const float* __restrict__ inW, const float* __restrict__ outW,
    const float* __restrict__ dtW, const float* __restrict__ s1W,
    const float* __restrict__ s2W,
    u16* imgb, u16* pWt, u16* inWt, u16* outWt, u16* dtWt, u16* s1t, u16* s2t)
{
    int b = blockIdx.x;
    if (b < 3072) {
        int idx = b*1024 + threadIdx.x*4;
        float4 v = *(const float4*)&img[idx];
        uint2 o;
        o.x = f2bf(v.x) | ((uint32_t)f2bf(v.y) << 16);
        o.y = f2bf(v.z) | ((uint32_t)f2bf(v.w) << 16);
        *(uint2*)&imgb[idx] = o;
        return;
    }
    b -= 3072;
    if (b < 384)  { tcast(pW, pWt, 768, 512, b); return; }
    b -= 384;
    if (b < 2048) { int blk=b>>10, t=b&1023; tcast(inW + (size_t)blk*512*2048, inWt + (size_t)blk*1048576, 512, 2048, t); return; }
    b -= 2048;
    if (b < 1024) { int blk=b>>9, t=b&511; tcast(outW + (size_t)blk*1024*512, outWt + (size_t)blk*524288, 1024, 512, t); return; }
    b -= 1024;
    if (b < 64)   { int blk=b>>5, t=b&31; tcast(dtW + (size_t)blk*32*1024, dtWt + (size_t)blk*32768, 32, 1024, t); return; }
    b -= 64;
    if (b < 256)  { tcast(s1W, s1t, 512, 512, b); return; }
    b -= 256;
    tcast(s2W, s2t, 512, 512, b);
}

// =============== assemble x = concat(cls, patches) + pos ===============
__global__ __launch_bounds__(256) void assemble_x(
    const float* __restrict__ tmp, const float* __restrict__ cls,
    const float* __restrict__ pos, float* __restrict__ x)
{
    int idx = blockIdx.x*256 + threadIdx.x;
    int d = idx & 511;
    int r = idx >> 9;
    int l = r % LSEQ;
    int b = r / LSEQ;
    float v = (l == 0) ? cls[d] : tmp[((size_t)(b*NPATCH + l-1))*DIM + d];
    x[idx] = v + pos[(size_t)l*DIM + d];
}

// =============== row LayerNorm (+gelu), 512 cols, dual f32/bf16 outputs ===============
__global__ __launch_bounds__(256) void ln_act(
    const float* __restrict__ in, const float* __restrict__ gw, const float* __restrict__ gb,
    float* __restrict__ f32out, u16* __restrict__ bf16out, int act)
{
    int row = blockIdx.x;
    const float* p = in + (size_t)row * 512;
    int t = threadIdx.x;
    float v0 = p[t], v1 = p[t + 256];
    float s = v0 + v1, q = v0*v0 + v1*v1;
    #pragma unroll
    for (int o = 32; o; o >>= 1) { s += __shfl_xor(s, o); q += __shfl_xor(q, o); }
    __shared__ float ls[4], lq[4];
    int w = t >> 6;
    if ((t & 63) == 0) { ls[w] = s; lq[w] = q; }
    __syncthreads();
    s = ls[0]+ls[1]+ls[2]+ls[3];
    q = lq[0]+lq[1]+lq[2]+lq[3];
    float mean = s * (1.f/512.f);
    float var  = q * (1.f/512.f) - mean*mean;
    float inv  = rsqrtf(var + 1e-5f);
    float o0 = (v0-mean)*inv*gw[t]     + gb[t];
    float o1 = (v1-mean)*inv*gw[t+256] + gb[t+256];
    if (act == 2) { o0 = geluf_(o0); o1 = geluf_(o1); }
    if (f32out)  { f32out[(size_t)row*512 + t] = o0; f32out[(size_t)row*512 + t + 256] = o1; }
    if (bf16out) { bf16out[(size_t)row*512 + t] = f2bf(o0); bf16out[(size_t)row*512 + t + 256] = f2bf(o1); }
}

// =============== causal depthwise conv (K=4) + SiLU, float4 per thread ===============
__global__ __launch_bounds__(256) void conv_silu(
    const float* __restrict__ xz, const float* __restrict__ cw,
    const float* __restrict__ cb, float* __restrict__ uo)
{
    int idx = blockIdx.x*256 + threadIdx.x;   // 4100*256 total
    int dq = idx & 255;
    int r  = idx >> 8;
    int b = r / LSEQ, l = r - b*LSEQ;
    int d0 = dq << 2;
    float4 w0 = *(const float4*)&cw[(d0+0)*4];
    float4 w1 = *(const float4*)&cw[(d0+1)*4];
    float4 w2 = *(const float4*)&cw[(d0+2)*4];
    float4 w3 = *(const float4*)&cw[(d0+3)*4];
    float4 acc = *(const float4*)&cb[d0];
    const float* wv0 = &w0.x; const float* wv1 = &w1.x;
    const float* wv2 = &w2.x; const float* wv3 = &w3.x;
    #pragma unroll
    for (int k = 0; k < KCONV; ++k) {
        int ls = l - (KCONV-1) + k;
        if (ls >= 0) {
            float4 v = *(const float4*)&xz[((size_t)(b*LSEQ + ls))*2048 + d0];
            acc.x = fmaf(wv0[k], v.x, acc.x);
            acc.y = fmaf(wv1[k], v.y, acc.y);
            acc.z = fmaf(wv2[k], v.z, acc.z);
            acc.w = fmaf(wv3[k], v.w, acc.w);
        }
    }
    acc.x *= sigmoidf_(acc.x);
    acc.y *= sigmoidf_(acc.y);
    acc.z *= sigmoidf_(acc.z);
    acc.w *= sigmoidf_(acc.w);
    *(float4*)&uo[(size_t)r*DIN + d0] = acc;
}

// =============== segmented selective scan (transposed LDS, b128 frags) ===============
// Phase 1: grid (64 dg, 4 b, 7 seg), block 256 = 16 dl x 16 n.
__global__ __launch_bounds__(256) void scan_phase1(
    const float* __restrict__ delta, const float* __restrict__ u,
    const float* __restrict__ xdbl,  const float* __restrict__ A_log,
    float* __restrict__ Aseg, float* __restrict__ Hseg)
{
    const int dg = blockIdx.x, b = blockIdx.y, s = blockIdx.z;
    const int tid = threadIdx.x;
    const int n = tid & 15, dl = tid >> 4;
    const int d0 = dg*16, d = d0 + dl;
    const float Adn2 = -__expf(A_log[(size_t)d*DSTATE + n]) * 1.44269504f;
    float sdv = 0.f, h = 0.f;
    __shared__ float sD[16][20], sU[16][20], sB[16][20];   // [d|n][t], stride 20 (16B aligned)
    const int tr = tid >> 4, tc = tid & 15;
    const size_t base = (size_t)b*LSEQ + (size_t)s*128;
    for (int c0 = 0; c0 < 128; c0 += 16) {
        __syncthreads();
        {
            size_t row = base + c0 + tr;
            sD[tc][tr] = delta[row*DIN + d0 + tc];
            sU[tc][tr] = u[row*DIN + d0 + tc];
            sB[tc][tr] = xdbl[row*64 + DTRANK + tc];
        }
        __syncthreads();
        #pragma unroll
        for (int hf = 0; hf < 2; ++hf) {
            f32x4 vD0 = *(const f32x4*)&sD[dl][hf*8];
            f32x4 vD1 = *(const f32x4*)&sD[dl][hf*8+4];
            f32x4 vU0 = *(const f32x4*)&sU[dl][hf*8];
            f32x4 vU1 = *(const f32x4*)&sU[dl][hf*8+4];
            f32x4 vB0 = *(const f32x4*)&sB[n][hf*8];
            f32x4 vB1 = *(const f32x4*)&sB[n][hf*8+4];
            #pragma unroll
            for (int t = 0; t < 8; ++t) {
                float dv = (t<4) ? vD0[t&3] : vD1[t&3];
                float uv = (t<4) ? vU0[t&3] : vU1[t&3];
                float Bv = (t<4) ? vB0[t&3] : vB1[t&3];
                sdv += dv;
                float dA = __builtin_exp2f(dv * Adn2);
                h = fmaf(dA, h, dv*uv*Bv);
            }
        }
    }
    int dn = d*DSTATE + n;
    Aseg[((size_t)b*7 + s)*16384 + dn] = __builtin_exp2f(Adn2 * sdv);
    Hseg[((size_t)b*8 + s)*16384 + dn] = h;
}

__global__ __launch_bounds__(256) void scan_mid(
    float* __restrict__ Hseg, const float* __restrict__ Aseg)
{
    int idx = blockIdx.x*256 + threadIdx.x;      // 65536
    int b = idx >> 14, dn = idx & 16383;
    float prev = 0.f;
    #pragma unroll
    for (int s = 0; s < 7; ++s) {
        size_t offH = ((size_t)b*8 + s)*16384 + dn;
        float a  = Aseg[((size_t)b*7 + s)*16384 + dn];
        float hs = Hseg[offH];
        Hseg[offH] = prev;
        prev = fmaf(a, prev, hs);
    }
    Hseg[((size_t)b*8 + 7)*16384 + dn] = prev;
}

// Phase 2: grid (64 dg, 4 b, 8 seg). cndmask-collect p; gating once per chunk, no divergence.
__global__ __launch_bounds__(256) void scan_phase2(
    const float* __restrict__ delta, const float* __restrict__ u,
    const float* __restrict__ xdbl,  const float* __restrict__ xz,
    const float* __restrict__ A_log, const float* __restrict__ Dp,
    const float* __restrict__ H0, u16* __restrict__ yb)
{
    const int dg = blockIdx.x, b = blockIdx.y, s = blockIdx.z;
    const int tid = threadIdx.x;
    const int n = tid & 15, dl = tid >> 4;
    const int d0 = dg*16, d = d0 + dl;
    const float Adn2 = -__expf(A_log[(size_t)d*DSTATE + n]) * 1.44269504f;
    const float Dd = Dp[d];
    float h = H0[((size_t)b*8 + s)*16384 + d*DSTATE + n];
    __shared__ float sD[16][20], sU[16][20], sZ[16][20], sB[16][20], sC[16][20];
    __shared__ u16 sY[16][20];
    const int tr = tid >> 4, tc = tid & 15;
    const size_t base = (size_t)b*LSEQ + (size_t)s*128;
    for (int c0 = 0; c0 < 128; c0 += 16) {
        __syncthreads();
        {
            size_t row = base + c0 + tr;
            sD[tc][tr] = delta[row*DIN + d0 + tc];
            sU[tc][tr] = u[row*DIN + d0 + tc];
            sZ[tc][tr] = xz[row*2048 + DIN + d0 + tc];
            sB[tc][tr] = xdbl[row*64 + DTRANK + tc];
            sC[tc][tr] = xdbl[row*64 + DTRANK + DSTATE + tc];
        }
        __syncthreads();
        float py = 0.f;
        #pragma unroll
        for (int hf = 0; hf < 2; ++hf) {
            f32x4 vD0 = *(const f32x4*)&sD[dl][hf*8];
            f32x4 vD1 = *(const f32x4*)&sD[dl][hf*8+4];
            f32x4 vU0 = *(const f32x4*)&sU[dl][hf*8];
            f32x4 vU1 = *(const f32x4*)&sU[dl][hf*8+4];
            f32x4 vB0 = *(const f32x4*)&sB[n][hf*8];
            f32x4 vB1 = *(const f32x4*)&sB[n][hf*8+4];
            f32x4 vC0 = *(const f32x4*)&sC[n][hf*8];
            f32x4 vC1 = *(const f32x4*)&sC[n][hf*8+4];
            #pragma unroll
            for (int t = 0; t < 8; ++t) {
                float dv = (t<4) ? vD0[t&3] : vD1[t&3];
                float uv = (t<4) ? vU0[t&3] : vU1[t&3];
                float Bv = (t<4) ? vB0[t&3] : vB1[t&3];
                float Cv = (t<4) ? vC0[t&3] : vC1[t&3];
                float dA = __builtin_exp2f(dv * Adn2);
                h = fmaf(dA, h, dv*uv*Bv);
                float pr = red16(h * Cv);
                int tt = hf*8 + t;
                py = (n == tt) ? pr : py;
            }
        }
        // epilogue: this thread finishes (t = n, d = d0+dl)
        {
            float uv = sU[dl][n];
            float zv = sZ[dl][n];
            float yv = (py + uv*Dd) * (zv * sigmoidf_(zv));
            sY[n][dl] = f2bf(yv);
        }
        __syncthreads();
        yb[(base + c0 + tr)*DIN + d0 + tc] = sY[tr][tc];
    }
    if (s == 7) {
        size_t row = (size_t)b*LSEQ + 1024;
        float dv = delta[row*DIN + d];
        float uv = u[row*DIN + d];
        float zv = xz[row*2048 + DIN + d];
        float Bv = xdbl[row*64 + DTRANK + n];
        float Cv = xdbl[row*64 + DTRANK + DSTATE + n];
        float dA = __builtin_exp2f(dv * Adn2);
        h = fmaf(dA, h, dv*uv*Bv);
        float p = red16(h * Cv);
        if (n == 0)
            yb[row*DIN + d] = f2bf((p + uv*Dd) * (zv * sigmoidf_(zv)));
    }
}

// =============== softmax-pool: phase 1 (per-segment partials) ===============
__global__ __launch_bounds__(256) void softpool_seg(
    const float* __restrict__ a, const float* __restrict__ yh,
    float* __restrict__ pm, float* __restrict__ ps, float* __restrict__ pp)
{
    int b   = blockIdx.y;
    int seg = blockIdx.z;
    int jj = threadIdx.x & 63;
    int j  = blockIdx.x * 64 + jj;
    int li = threadIdx.x >> 6;
    int lbeg = seg * 64;
    int lend = min(lbeg + 64, LSEQ);
    float m = -3.0e38f, s = 0.f, p = 0.f;
    for (int l = lbeg + li; l < lend; l += 4) {
        size_t off = ((size_t)(b*LSEQ + l))*OUTD + j;
        float av = a[off], yv = yh[off];
        float mn = fmaxf(m, av);
        float sc = __expf(m - mn);
        float e  = __expf(av - mn);
        s = s*sc + e;
        p = p*sc + yv*e;
        m = mn;
    }
    __shared__ float sm[4][64], ss[4][64], sp[4][64];
    sm[li][jj] = m; ss[li][jj] = s; sp[li][jj] = p;
    __syncthreads();
    if (li == 0) {
        #pragma unroll
        for (int k2 = 1; k2 < 4; ++k2) {
            float m2 = sm[k2][jj], s2 = ss[k2][jj], p2 = sp[k2][jj];
            float M2 = fmaxf(m, m2);
            float c1 = __expf(m - M2), c2 = __expf(m2 - M2);
            s = s*c1 + s2*c2;
            p = p*c1 + p2*c2;
            m = M2;
        }
        int o = ((seg*B_ + b)*OUTD) + j;
        pm[o] = m; ps[o] = s; pp[o] = p;
    }
}

__global__ __launch_bounds__(256) void softpool_combine(
    const float* __restrict__ pm, const float* __restrict__ ps,
    const float* __restrict__ pp, float* __restrict__ pooled)
{
    int idx = blockIdx.x*256 + threadIdx.x;   // 2048 total
    int b = idx >> 9, j = idx & 511;
    float m = -3.0e38f, s = 0.f, p = 0.f;
    #pragma unroll
    for (int seg = 0; seg < NSEG_SP; ++seg) {
        int o = ((seg*B_ + b)*OUTD) + j;
        float m2 = pm[o], s2 = ps[o], p2 = pp[o];
        float M2 = fmaxf(m, m2);
        float c1 = __expf(m - M2), c2 = __expf(m2 - M2);
        s = s*c1 + s2*c2;
        p = p*c1 + p2*c2;
        m = M2;
    }
    pooled[(size_t)b*OUTD + j] = p / s;
}

extern "C" void kernel_launch(void* const* d_in, const int* in_sizes, int n_in,
                              void* d_out, int out_size, void* d_ws, size_t ws_size,
                              hipStream_t stream) {
    const float* img     = (const float*)d_in[0];
    const float* patch_W = (const float*)d_in[1];
    const float* patch_b = (const float*)d_in[2];
    const float* pos_emb = (const float*)d_in[3];
    const float* cls_tok = (const float*)d_in[4];
    const float* ln_w    = (const float*)d_in[5];
    const float* ln_b    = (const float*)d_in[6];
    const float* in_W    = (const float*)d_in[7];
    const float* conv_w  = (const float*)d_in[8];
    const float* conv_b  = (const float*)d_in[9];
    const float* xproj_W = (const float*)d_in[10];
    const float* dt_W    = (const float*)d_in[11];
    const float* dt_b    = (const float*)d_in[12];
    const float* A_log   = (const float*)d_in[13];
    const float* Dp      = (const float*)d_in[14];
    const float* out_W   = (const float*)d_in[15];
    const float* sl1_W   = (const float*)d_in[16];
    const float* sl1_b   = (const float*)d_in[17];
    const float* sl1_lnw = (const float*)d_in[18];
    const float* sl1_lnb = (const float*)d_in[19];
    const float* sl2_W   = (const float*)d_in[20];
    const float* sl2_b   = (const float*)d_in[21];
    const float* sl2_lnw = (const float*)d_in[22];
    const float* sl2_lnb = (const float*)d_in[23];
    const float* lat_lnw = (const float*)d_in[24];
    const float* lat_lnb = (const float*)d_in[25];
    float* out = (float*)d_out;
    float* ws  = (float*)d_ws;

    // ---- f32 workspace (floats) ----
    float* x     = ws + 0;          // 2,099,200
    float* xz    = ws + 2099200;    // 8,396,800  (head: yh @ +0, t2 @ +2,099,200)
    float* u     = ws + 10496000;   // 4,198,400  (head: a)
    float* xdbl  = ws + 14694400;   //   262,400  (head: pooled + softpool partials)
    float* delta = ws + 14956800;   // 4,198,400  (patch tmp / xproj partials / head t1)
    // ---- bf16 workspace (u16) ----
    u16* ub      = (u16*)(ws + 19155200);
    u16* regA    = ub + 0;          // img_bf / y_bf / yh_bf
    u16* regB    = ub + 4325376;    // xn_bf / scan segbufs / x_bf
    u16* xdbl_bf = ub + 6488064;
    u16* pWt     = ub + 6758400;
    u16* inWt    = ub + 7151616;
    u16* outWt   = ub + 9248768;
    u16* dtWt    = ub + 10297344;
    u16* s1t     = ub + 10362880;
    u16* s2t     = ub + 10625024;

    float* yh     = xz;
    float* t2     = xz + 2099200;
    float* a      = u;
    float* pooled = xdbl;
    float* spm    = xdbl + 8192;
    float* sps    = spm + 34816;
    float* spp    = sps + 34816;
    float* t1     = delta;
    float* segH   = (float*)regB;
    float* segA   = segH + 524288;
    float* xprojP = delta;

    // 0) prep
    prep_kernel<<<7104, 256, 0, stream>>>(img, patch_W, in_W, out_W, dt_W, sl1_W, sl2_W,
                                          regA, pWt, inWt, outWt, dtWt, s1t, s2t);

    // 1) patch GEMM + assemble
    gemm_mfma<2><<<dim3(512/128, 4096/64), 256, 0, stream>>>(
        regA, PDIM, pWt, delta, DIM, 4096, DIM, PDIM, patch_b, nullptr, 0, nullptr);
    assemble_x<<<(MROWS*DIM)/256, 256, 0, stream>>>(delta, cls_tok, pos_emb, x);

    // 2) mamba blocks
    for (int i = 0; i < NBLK; ++i) {
        ln_act<<<MROWS, 256, 0, stream>>>(x, ln_w + i*DIM, ln_b + i*DIM,
                                          nullptr, regB, 0);
        gemm_mfma<4><<<dim3(2048/128, 33), 256, 0, stream>>>(
            regB, DIM, inWt + (size_t)i*1048576, xz, 2*DIN,
            MROWS, 2*DIN, DIM, nullptr, nullptr, 0, nullptr);
        conv_silu<<<MROWS, 256, 0, stream>>>(
            xz, conv_w + i*DIN*KCONV, conv_b + i*DIN, u);
        xproj_gemm<<<dim3(65, 4), 256, 0, stream>>>(
            u, xproj_W + (size_t)i*DIN*64, xprojP);
        xproj_reduce<<<1025, 256, 0, stream>>>(xprojP, xdbl, xdbl_bf);
        gemm_mfma<2><<<dim3(1024/128, 65), 256, 0, stream>>>(
            xdbl_bf, 64, dtWt + (size_t)i*32768, delta, DIN,
            MROWS, DIN, DTRANK, dt_b + i*DIN, nullptr, 1, nullptr);
        scan_phase1<<<dim3(64, 4, 7), 256, 0, stream>>>(
            delta, u, xdbl, A_log + (size_t)i*DIN*DSTATE, segA, segH);
        scan_mid<<<256, 256, 0, stream>>>(segH, segA);
        scan_phase2<<<dim3(64, 4, 8), 256, 0, stream>>>(
            delta, u, xdbl, xz, A_log + (size_t)i*DIN*DSTATE, Dp + i*DIN,
            segH, regA);
        gemm_mfma<2><<<dim3(512/128, 65), 256, 0, stream>>>(
            regA, DIN, outWt + (size_t)i*524288, x, DIM,
            MROWS, DIM, DIN, nullptr, x, 0, (i == NBLK-1) ? regB : nullptr);
    }

    // 3) head
    gemm_mfma<2><<<dim3(512/128, 65), 256, 0, stream>>>(
        regB, DIM, s1t, t1, OUTD, MROWS, OUTD, DIM, sl1_b, nullptr, 0, nullptr);
    ln_act<<<MROWS, 256, 0, stream>>>(t1, sl1_lnw, sl1_lnb, yh, regA, 2);
    gemm_mfma<2><<<dim3(512/128, 65), 256, 0, stream>>>(
        regA, OUTD, s2t, t2, OUTD, MROWS, OUTD, OUTD, sl2_b, nullptr, 0, nullptr);
    ln_act<<<MROWS, 256, 0, stream>>>(t2, sl2_lnw, sl2_lnb, a, nullptr, 2);
    softpool_seg<<<dim3(OUTD/64, B_, NSEG_SP), 256, 0, stream>>>(a, yh, spm, sps, spp);
    softpool_combine<<<8, 256, 0, stream>>>(spm, sps, spp, pooled);
    ln_act<<<B_, 256, 0, stream>>>(pooled, lat_lnw, lat_lnb, out, nullptr, 0);
}

// Round 7
// 610.087 us; speedup vs baseline: 2.5852x; 1.0361x over previous
//
#include <hip/hip_runtime.h>
#include <cstdint>
#include <cstddef>

#define B_     4
#define NPATCH 1024
#define LSEQ   1025
#define PDIM   768
#define DIM    512
#define OUTD   512
#define DIN    1024
#define DSTATE 16
#define DTRANK 32
#define KCONV  4
#define NBLK   2
#define MROWS  (B_*LSEQ)   // 4100
#define NSEG_SP 17

typedef unsigned short u16;
typedef __attribute__((ext_vector_type(8))) short bf16x8;
typedef __attribute__((ext_vector_type(4))) float f32x4;

__device__ __forceinline__ float sigmoidf_(float x){ return 1.f/(1.f+__expf(-x)); }
__device__ __forceinline__ float geluf_(float x){ return 0.5f*x*(1.f+erff(x*0.70710678118654752f)); }
__device__ __forceinline__ u16 f2bf(float x){
    uint32_t b = __float_as_uint(x);
    b += 0x7FFFu + ((b >> 16) & 1u);
    return (u16)(b >> 16);
}
__device__ __forceinline__ float bf2f(u16 v){ return __uint_as_float((uint32_t)v << 16); }
template<int CTRL>
__device__ __forceinline__ float dppmov(float x){
    return __int_as_float(__builtin_amdgcn_update_dpp(0, __float_as_int(x), CTRL, 0xF, 0xF, true));
}
__device__ __forceinline__ float red16(float p){
    p += dppmov<0xB1>(p);
    p += dppmov<0x4E>(p);
    p += dppmov<0x141>(p);
    p += dppmov<0x140>(p);
    return p;
}
__device__ __forceinline__ void gload16(const void* g, void* l){
    __builtin_amdgcn_global_load_lds((const __attribute__((address_space(1))) void*)g,
                                     (__attribute__((address_space(3))) void*)l, 16, 0, 0);
}
__device__ __forceinline__ float softplusf_(float v){
    return (v > 20.f) ? v : log1pf(__expf(v));
}

// =============== bf16 MFMA NT GEMM: C[M,N] = A[M,K]bf16 @ Wt[N,K]bf16^T ===============
// C (f32) and bf16out are both optional. XOR-swizzled LDS (pre-swizzled global source).
template<int MF>
__global__ __launch_bounds__(256) void gemm_mfma(
    const u16* __restrict__ A, int lda,
    const u16* __restrict__ Wt,
    float* __restrict__ C, int ldc,
    int M, int N, int K,
    const float* __restrict__ bias,
    const float* __restrict__ addsrc,
    int act, u16* __restrict__ bf16out)
{
    __shared__ u16 lsA[MF*32*32];
    __shared__ u16 lsB[128*32];
    const int tid = threadIdx.x;
    const int wid = tid >> 6, lane = tid & 63;
    const int m0 = blockIdx.y * (MF*32), n0 = blockIdx.x * 128;
    const int wm = (wid>>1)*(MF*16), wn = (wid&1)*64;
    f32x4 acc[MF][4] = {};

    const char* Agp = (const char*)(A + (size_t)m0 * lda);
    const char* Bgp = (const char*)(Wt + (size_t)n0 * K);
    const int lrow = lane >> 2;
    const int lcb  = (((lane & 3) ^ ((lane >> 3) & 3))) * 16;
    const int rsw  = ((lane & 15) >> 1) & 3;
    const int acol = ((lane >> 4) ^ rsw) * 8;

    for (int k0 = 0; k0 < K; k0 += 32) {
        {
            int ra = wid*(MF*8) + lrow;
            gload16(Agp + (size_t)ra*(lda*2) + k0*2 + lcb, &lsA[(wid*(MF*8))*32]);
            if constexpr (MF == 4) {
                gload16(Agp + (size_t)(ra+16)*(lda*2) + k0*2 + lcb, &lsA[(wid*(MF*8)+16)*32]);
            }
        }
        {
            int rb = wid*32 + lrow;
            gload16(Bgp + (size_t)rb*(K*2) + k0*2 + lcb, &lsB[(wid*32)*32]);
            gload16(Bgp + (size_t)(rb+16)*(K*2) + k0*2 + lcb, &lsB[(wid*32+16)*32]);
        }
        __syncthreads();
        bf16x8 af[MF], bfr[4];
        #pragma unroll
        for (int i = 0; i < MF; ++i)
            af[i] = *(const bf16x8*)&lsA[(wm + i*16 + (lane&15))*32 + acol];
        #pragma unroll
        for (int j = 0; j < 4; ++j)
            bfr[j] = *(const bf16x8*)&lsB[(wn + j*16 + (lane&15))*32 + acol];
        #pragma unroll
        for (int i = 0; i < MF; ++i)
            #pragma unroll
            for (int j = 0; j < 4; ++j)
                acc[i][j] = __builtin_amdgcn_mfma_f32_16x16x32_bf16(af[i], bfr[j], acc[i][j], 0, 0, 0);
        __syncthreads();
    }
    #pragma unroll
    for (int i = 0; i < MF; ++i) {
        #pragma unroll
        for (int j = 0; j < 4; ++j) {
            int col = n0 + wn + j*16 + (lane & 15);
            float bv = bias ? bias[col] : 0.f;
            #pragma unroll
            for (int r = 0; r < 4; ++r) {
                int row = m0 + wm + i*16 + (lane>>4)*4 + r;
                if (row < M) {
                    float v = acc[i][j][r] + bv;
                    if (addsrc) v += addsrc[(size_t)row*ldc + col];
                    if (act == 1) v = softplusf_(v);
                    if (C) C[(size_t)row*ldc + col] = v;
                    if (bf16out) bf16out[(size_t)row*ldc + col] = f2bf(v);
                }
            }
        }
    }
}

// =============== xproj split-K f32 GEMM: P[kc][4100][64] partials ===============
__global__ __launch_bounds__(256) void xproj_gemm(
    const float* __restrict__ Au,
    const float* __restrict__ W,
    float* __restrict__ P)
{
    __shared__ float As[16][68];
    __shared__ float Bs[16][68];
    int tid = threadIdx.x;
    int tx = tid & 15, ty = tid >> 4;
    int m0 = blockIdx.x * 64;
    int kbase = blockIdx.y * 256;
    float acc[4][4] = {};
    for (int k0 = kbase; k0 < kbase + 256; k0 += 16) {
        {
            int r  = tid >> 2;
            int kq = (tid & 3) << 2;
            float4 va = make_float4(0.f,0.f,0.f,0.f);
            int gr = m0 + r;
            if (gr < MROWS) va = *reinterpret_cast<const float4*>(Au + (size_t)gr*DIN + k0 + kq);
            As[kq+0][r]=va.x; As[kq+1][r]=va.y; As[kq+2][r]=va.z; As[kq+3][r]=va.w;
        }
        {
            int kk = tid >> 4;
            int nq = (tid & 15) << 2;
            float4 vb = *reinterpret_cast<const float4*>(W + (size_t)(k0+kk)*64 + nq);
            Bs[kk][nq+0]=vb.x; Bs[kk][nq+1]=vb.y; Bs[kk][nq+2]=vb.z; Bs[kk][nq+3]=vb.w;
        }
        __syncthreads();
        #pragma unroll
        for (int k = 0; k < 16; ++k) {
            float a0=As[k][ty*4+0],a1=As[k][ty*4+1],a2=As[k][ty*4+2],a3=As[k][ty*4+3];
            float b0=Bs[k][tx*4+0],b1=Bs[k][tx*4+1],b2=Bs[k][tx*4+2],b3=Bs[k][tx*4+3];
            acc[0][0]=fmaf(a0,b0,acc[0][0]); acc[0][1]=fmaf(a0,b1,acc[0][1]);
            acc[0][2]=fmaf(a0,b2,acc[0][2]); acc[0][3]=fmaf(a0,b3,acc[0][3]);
            acc[1][0]=fmaf(a1,b0,acc[1][0]); acc[1][1]=fmaf(a1,b1,acc[1][1]);
            acc[1][2]=fmaf(a1,b2,acc[1][2]); acc[1][3]=fmaf(a1,b3,acc[1][3]);
            acc[2][0]=fmaf(a2,b0,acc[2][0]); acc[2][1]=fmaf(a2,b1,acc[2][1]);
            acc[2][2]=fmaf(a2,b2,acc[2][2]); acc[2][3]=fmaf(a2,b3,acc[2][3]);
            acc[3][0]=fmaf(a3,b0,acc[3][0]); acc[3][1]=fmaf(a3,b1,acc[3][1]);
            acc[3][2]=fmaf(a3,b2,acc[3][2]); acc[3][3]=fmaf(a3,b3,acc[3][3]);
        }
        __syncthreads();
    }
    float* Pp = P + (size_t)blockIdx.y * (MROWS*64);
    #pragma unroll
    for (int i = 0; i < 4; ++i) {
        int r = m0 + ty*4 + i;
        if (r >= MROWS) continue;
        #pragma unroll
        for (int j = 0; j < 4; ++j)
            Pp[(size_t)r*64 + tx*4 + j] = acc[i][j];
    }
}

__global__ __launch_bounds__(256) void xproj_reduce(
    const float* __restrict__ P, float* __restrict__ xdbl)
{
    int idx = blockIdx.x*256 + threadIdx.x;
    xdbl[idx] = P[idx] + P[MROWS*64 + idx] + P[2*MROWS*64 + idx] + P[3*MROWS*64 + idx];
}

// =============== prep: img cast + weight transpose-casts ===============
__device__ void tcast(const float* __restrict__ in, u16* __restrict__ outp,
                      int K, int N, int tix)
{
    __shared__ float tl[32][33];
    int ntn = N >> 5;
    int tk = tix / ntn, tn = tix - tk*ntn;
    int tid = threadIdx.x;
    int r = tid >> 3, c0 = (tid & 7) << 2;
    float4 v = *(const float4*)&in[(size_t)(tk*32 + r)*N + tn*32 + c0];
    tl[r][c0+0]=v.x; tl[r][c0+1]=v.y; tl[r][c0+2]=v.z; tl[r][c0+3]=v.w;
    __syncthreads();
    int nn = r, k0 = c0;
    uint32_t w0 = f2bf(tl[k0+0][nn]) | ((uint32_t)f2bf(tl[k0+1][nn]) << 16);
    uint32_t w1 = f2bf(tl[k0+2][nn]) | ((uint32_t)f2bf(tl[k0+3][nn]) << 16);
    uint2 o; o.x = w0; o.y = w1;
    *(uint2*)&outp[(size_t)(tn*32 + nn)*K + tk*32 + k0] = o;
}

__global__ __launch_bounds__(256) void prep_kernel(
    const float* __restrict__ img, const float* __restrict__ pW,
    const float* __restrict__ inW, const float* __restrict__ outW,
    const float* __restrict__ s1W, const float* __restrict__ s2W,
    u16* imgb, u16* pWt, u16* inWt, u16* outWt, u16* s1t, u16* s2t)
{
    int b = blockIdx.x;
    if (b < 3072) {
        int idx = b*1024 + threadIdx.x*4;
        float4 v = *(const float4*)&img[idx];
        uint2 o;
        o.x = f2bf(v.x) | ((uint32_t)f2bf(v.y) << 16);
        o.y = f2bf(v.z) | ((uint32_t)f2bf(v.w) << 16);
        *(uint2*)&imgb[idx] = o;
        return;
    }
    b -= 3072;
    if (b < 384)  { tcast(pW, pWt, 768, 512, b); return; }
    b -= 384;
    if (b < 2048) { int blk=b>>10, t=b&1023; tcast(inW + (size_t)blk*512*2048, inWt + (size_t)blk*1048576, 512, 2048, t); return; }
    b -= 2048;
    if (b < 1024) { int blk=b>>9, t=b&511; tcast(outW + (size_t)blk*1024*512, outWt + (size_t)blk*524288, 1024, 512, t); return; }
    b -= 1024;
    if (b < 256)  { tcast(s1W, s1t, 512, 512, b); return; }
    b -= 256;
    tcast(s2W, s2t, 512, 512, b);
}

// =============== assemble x = concat(cls, patches) + pos ===============
__global__ __launch_bounds__(256) void assemble_x(
    const float* __restrict__ tmp, const float* __restrict__ cls,
    const float* __restrict__ pos, float* __restrict__ x)
{
    int idx = blockIdx.x*256 + threadIdx.x;
    int d = idx & 511;
    int r = idx >> 9;
    int l = r % LSEQ;
    int b = r / LSEQ;
    float v = (l == 0) ? cls[d] : tmp[((size_t)(b*NPATCH + l-1))*DIM + d];
    x[idx] = v + pos[(size_t)l*DIM + d];
}

// =============== row LayerNorm (+gelu), 512 cols ===============
__global__ __launch_bounds__(256) void ln_act(
    const float* __restrict__ in, const float* __restrict__ gw, const float* __restrict__ gb,
    float* __restrict__ f32out, u16* __restrict__ bf16out, int act)
{
    int row = blockIdx.x;
    const float* p = in + (size_t)row * 512;
    int t = threadIdx.x;
    float v0 = p[t], v1 = p[t + 256];
    float s = v0 + v1, q = v0*v0 + v1*v1;
    #pragma unroll
    for (int o = 32; o; o >>= 1) { s += __shfl_xor(s, o); q += __shfl_xor(q, o); }
    __shared__ float ls[4], lq[4];
    int w = t >> 6;
    if ((t & 63) == 0) { ls[w] = s; lq[w] = q; }
    __syncthreads();
    s = ls[0]+ls[1]+ls[2]+ls[3];
    q = lq[0]+lq[1]+lq[2]+lq[3];
    float mean = s * (1.f/512.f);
    float var  = q * (1.f/512.f) - mean*mean;
    float inv  = rsqrtf(var + 1e-5f);
    float o0 = (v0-mean)*inv*gw[t]     + gb[t];
    float o1 = (v1-mean)*inv*gw[t+256] + gb[t+256];
    if (act == 2) { o0 = geluf_(o0); o1 = geluf_(o1); }
    if (f32out)  { f32out[(size_t)row*512 + t] = o0; f32out[(size_t)row*512 + t + 256] = o1; }
    if (bf16out) { bf16out[(size_t)row*512 + t] = f2bf(o0); bf16out[(size_t)row*512 + t + 256] = f2bf(o1); }
}

// =============== causal depthwise conv (K=4) + SiLU, bf16 in, f32 out ===============
__global__ __launch_bounds__(256) void conv_silu(
    const u16* __restrict__ xzb, const float* __restrict__ cw,
    const float* __restrict__ cb, float* __restrict__ uo)
{
    int idx = blockIdx.x*256 + threadIdx.x;   // 4100*256 total
    int dq = idx & 255;
    int r  = idx >> 8;
    int b = r / LSEQ, l = r - b*LSEQ;
    int d0 = dq << 2;
    float4 w0 = *(const float4*)&cw[(d0+0)*4];
    float4 w1 = *(const float4*)&cw[(d0+1)*4];
    float4 w2 = *(const float4*)&cw[(d0+2)*4];
    float4 w3 = *(const float4*)&cw[(d0+3)*4];
    float4 acc = *(const float4*)&cb[d0];
    const float* wv0 = &w0.x; const float* wv1 = &w1.x;
    const float* wv2 = &w2.x; const float* wv3 = &w3.x;
    #pragma unroll
    for (int k = 0; k < KCONV; ++k) {
        int ls = l - (KCONV-1) + k;
        if (ls >= 0) {
            ushort4 v = *(const ushort4*)&xzb[((size_t)(b*LSEQ + ls))*2048 + d0];
            acc.x = fmaf(wv0[k], bf2f(v.x), acc.x);
            acc.y = fmaf(wv1[k], bf2f(v.y), acc.y);
            acc.z = fmaf(wv2[k], bf2f(v.z), acc.z);
            acc.w = fmaf(wv3[k], bf2f(v.w), acc.w);
        }
    }
    acc.x *= sigmoidf_(acc.x);
    acc.y *= sigmoidf_(acc.y);
    acc.z *= sigmoidf_(acc.z);
    acc.w *= sigmoidf_(acc.w);
    *(float4*)&uo[(size_t)r*DIN + d0] = acc;
}

// =============== segmented selective scan with FUSED dt-proj + softplus ===============
// Phase 1: grid (64 dg, 4 b, 7 seg), block 256.
__global__ __launch_bounds__(256) void scan_phase1(
    const float* __restrict__ u,    const float* __restrict__ xdbl,
    const float* __restrict__ dtW,  const float* __restrict__ dtb,
    const float* __restrict__ A_log,
    float* __restrict__ Aseg, float* __restrict__ Hseg)
{
    const int dg = blockIdx.x, b = blockIdx.y, s = blockIdx.z;
    const int tid = threadIdx.x;
    const int n = tid & 15, dl = tid >> 4;
    const int tr = tid >> 4, tc = tid & 15;
    const int d0 = dg*16, d = d0 + dl;
    const float Adn2 = -__expf(A_log[(size_t)d*DSTATE + n]) * 1.44269504f;
    __shared__ float sX[16][68];     // xdbl rows [t][64]
    __shared__ float sW[32][17];     // dtW slice [k][dcol]
    __shared__ float sU[16][20];     // [d][t]
    __shared__ float sDel[16][20];   // [d][t]
    {
        int k = tid >> 4;
        sW[k][tc]    = dtW[(size_t)k*DIN + d0 + tc];
        sW[k+16][tc] = dtW[(size_t)(k+16)*DIN + d0 + tc];
    }
    const float db = dtb[d0 + tc];
    float sdv = 0.f, h = 0.f;
    const size_t base = (size_t)b*LSEQ + (size_t)s*128;
    for (int c0 = 0; c0 < 128; c0 += 16) {
        __syncthreads();
        {
            size_t row = base + c0 + tr;
            *(float4*)&sX[tr][tc*4] = *(const float4*)&xdbl[row*64 + tc*4];
            sU[tc][tr] = u[row*DIN + d0 + tc];
        }
        __syncthreads();
        {   // delta: thread (tr=t, tc=dcol)
            float acc = db;
            #pragma unroll
            for (int k = 0; k < 32; ++k) acc = fmaf(sX[tr][k], sW[k][tc], acc);
            sDel[tc][tr] = softplusf_(acc);
        }
        __syncthreads();
        #pragma unroll
        for (int hf = 0; hf < 2; ++hf) {
            f32x4 vD0 = *(const f32x4*)&sDel[dl][hf*8];
            f32x4 vD1 = *(const f32x4*)&sDel[dl][hf*8+4];
            f32x4 vU0 = *(const f32x4*)&sU[dl][hf*8];
            f32x4 vU1 = *(const f32x4*)&sU[dl][hf*8+4];
            #pragma unroll
            for (int t = 0; t < 8; ++t) {
                float dv = (t<4) ? vD0[t&3] : vD1[t&3];
                float uv = (t<4) ? vU0[t&3] : vU1[t&3];
                float Bv = sX[hf*8+t][32+n];
                sdv += dv;
                h = fmaf(__builtin_exp2f(dv * Adn2), h, dv*uv*Bv);
            }
        }
    }
    int dn = d*DSTATE + n;
    Aseg[((size_t)b*7 + s)*16384 + dn] = __builtin_exp2f(Adn2 * sdv);
    Hseg[((size_t)b*8 + s)*16384 + dn] = h;
}

__global__ __launch_bounds__(256) void scan_mid(
    float* __restrict__ Hseg, const float* __restrict__ Aseg)
{
    int idx = blockIdx.x*256 + threadIdx.x;
    int b = idx >> 14, dn = idx & 16383;
    float prev = 0.f;
    #pragma unroll
    for (int s = 0; s < 7; ++s) {
        size_t offH = ((size_t)b*8 + s)*16384 + dn;
        float a  = Aseg[((size_t)b*7 + s)*16384 + dn];
        float hs = Hseg[offH];
        Hseg[offH] = prev;
        prev = fmaf(a, prev, hs);
    }
    Hseg[((size_t)b*8 + 7)*16384 + dn] = prev;
}

// Phase 2: grid (64 dg, 4 b, 8 seg), block 256. Fused dt-proj; emits gated y bf16.
__global__ __launch_bounds__(256) void scan_phase2(
    const float* __restrict__ u,    const float* __restrict__ xdbl,
    const u16*   __restrict__ xzb,  const float* __restrict__ dtW,
    const float* __restrict__ dtb,  const float* __restrict__ A_log,
    const float* __restrict__ Dp,   const float* __restrict__ H0,
    u16* __restrict__ yb)
{
    const int dg = blockIdx.x, b = blockIdx.y, s = blockIdx.z;
    const int tid = threadIdx.x;
    const int n = tid & 15, dl = tid >> 4;
    const int tr = tid >> 4, tc = tid & 15;
    const int d0 = dg*16, d = d0 + dl;
    const float Adn2 = -__expf(A_log[(size_t)d*DSTATE + n]) * 1.44269504f;
    const float Dd = Dp[d];
    float h = H0[((size_t)b*8 + s)*16384 + d*DSTATE + n];
    __shared__ float sX[16][68];
    __shared__ float sW[32][17];
    __shared__ float sU[16][20];
    __shared__ float sDel[16][20];
    __shared__ float sZ[16][20];
    __shared__ u16 sY[16][17];
    {
        int k = tid >> 4;
        sW[k][tc]    = dtW[(size_t)k*DIN + d0 + tc];
        sW[k+16][tc] = dtW[(size_t)(k+16)*DIN + d0 + tc];
    }
    const float db = dtb[d0 + tc];
    const size_t base = (size_t)b*LSEQ + (size_t)s*128;
    for (int c0 = 0; c0 < 128; c0 += 16) {
        {
            size_t row = base + c0 + tr;
            *(float4*)&sX[tr][tc*4] = *(const float4*)&xdbl[row*64 + tc*4];
            sU[tc][tr] = u[row*DIN + d0 + tc];
            sZ[tc][tr] = bf2f(xzb[row*2048 + DIN + d0 + tc]);
        }
        __syncthreads();
        {
            float acc = db;
            #pragma unroll
            for (int k = 0; k < 32; ++k) acc = fmaf(sX[tr][k], sW[k][tc], acc);
            sDel[tc][tr] = softplusf_(acc);
        }
        __syncthreads();
        float py = 0.f;
        #pragma unroll
        for (int hf = 0; hf < 2; ++hf) {
            f32x4 vD0 = *(const f32x4*)&sDel[dl][hf*8];
            f32x4 vD1 = *(const f32x4*)&sDel[dl][hf*8+4];
            f32x4 vU0 = *(const f32x4*)&sU[dl][hf*8];
            f32x4 vU1 = *(const f32x4*)&sU[dl][hf*8+4];
            #pragma unroll
            for (int t = 0; t < 8; ++t) {
                float dv = (t<4) ? vD0[t&3] : vD1[t&3];
                float uv = (t<4) ? vU0[t&3] : vU1[t&3];
                int tt = hf*8 + t;
                float Bv = sX[tt][32+n];
                float Cv = sX[tt][48+n];
                h = fmaf(__builtin_exp2f(dv * Adn2), h, dv*uv*Bv);
                float pr = red16(h * Cv);
                py = (n == tt) ? pr : py;
            }
        }
        {   // thread (dl, n) finishes output (t=n, d=d0+dl)
            float uv = sU[dl][n];
            float zv = sZ[dl][n];
            sY[n][dl] = f2bf((py + uv*Dd) * (zv * sigmoidf_(zv)));
        }
        __syncthreads();
        yb[(base + c0 + tr)*DIN + d0 + tc] = sY[tr][tc];
    }
    if (s == 7) {
        size_t row = (size_t)b*LSEQ + 1024;
        float acc = dtb[d];
        #pragma unroll
        for (int k = 0; k < 32; ++k)
            acc = fmaf(xdbl[row*64 + k], dtW[(size_t)k*DIN + d], acc);
        float dv = softplusf_(acc);
        float uv = u[row*DIN + d];
        float zv = bf2f(xzb[row*2048 + DIN + d]);
        float Bv = xdbl[row*64 + DTRANK + n];
        float Cv = xdbl[row*64 + DTRANK + DSTATE + n];
        h = fmaf(__builtin_exp2f(dv * Adn2), h, dv*uv*Bv);
        float p = red16(h * Cv);
        if (n == 0)
            yb[row*DIN + d] = f2bf((p + uv*Dd) * (zv * sigmoidf_(zv)));
    }
}

// =============== softmax-pool ===============
__global__ __launch_bounds__(256) void softpool_seg(
    const float* __restrict__ a, const float* __restrict__ yh,
    float* __restrict__ pm, float* __restrict__ ps, float* __restrict__ pp)
{
    int b   = blockIdx.y;
    int seg = blockIdx.z;
    int jj = threadIdx.x & 63;
    int j  = blockIdx.x * 64 + jj;
    int li = threadIdx.x >> 6;
    int lbeg = seg * 64;
    int lend = min(lbeg + 64, LSEQ);
    float m = -3.0e38f, s = 0.f, p = 0.f;
    for (int l = lbeg + li; l < lend; l += 4) {
        size_t off = ((size_t)(b*LSEQ + l))*OUTD + j;
        float av = a[off], yv = yh[off];
        float mn = fmaxf(m, av);
        float sc = __expf(m - mn);
        float e  = __expf(av - mn);
        s = s*sc + e;
        p = p*sc + yv*e;
        m = mn;
    }
    __shared__ float sm[4][64], ss[4][64], sp[4][64];
    sm[li][jj] = m; ss[li][jj] = s; sp[li][jj] = p;
    __syncthreads();
    if (li == 0) {
        #pragma unroll
        for (int k2 = 1; k2 < 4; ++k2) {
            float m2 = sm[k2][jj], s2 = ss[k2][jj], p2 = sp[k2][jj];
            float M2 = fmaxf(m, m2);
            float c1 = __expf(m - M2), c2 = __expf(m2 - M2);
            s = s*c1 + s2*c2;
            p = p*c1 + p2*c2;
            m = M2;
        }
        int o = ((seg*B_ + b)*OUTD) + j;
        pm[o] = m; ps[o] = s; pp[o] = p;
    }
}

__global__ __launch_bounds__(256) void softpool_combine(
    const float* __restrict__ pm, const float* __restrict__ ps,
    const float* __restrict__ pp, float* __restrict__ pooled)
{
    int idx = blockIdx.x*256 + threadIdx.x;
    int b = idx >> 9, j = idx & 511;
    float m = -3.0e38f, s = 0.f, p = 0.f;
    #pragma unroll
    for (int seg = 0; seg < NSEG_SP; ++seg) {
        int o = ((seg*B_ + b)*OUTD) + j;
        float m2 = pm[o], s2 = ps[o], p2 = pp[o];
        float M2 = fmaxf(m, m2);
        float c1 = __expf(m - M2), c2 = __expf(m2 - M2);
        s = s*c1 + s2*c2;
        p = p*c1 + p2*c2;
        m = M2;
    }
    pooled[(size_t)b*OUTD + j] = p / s;
}

extern "C" void kernel_launch(void* const* d_in, const int* in_sizes, int n_in,
                              void* d_out, int out_size, void* d_ws, size_t ws_size,
                              hipStream_t stream) {
    const float* img     = (const float*)d_in[0];
    const float* patch_W = (const float*)d_in[1];
    const float* patch_b = (const float*)d_in[2];
    const float* pos_emb = (const float*)d_in[3];
    const float* cls_tok = (const float*)d_in[4];
    const float* ln_w    = (const float*)d_in[5];
    const float* ln_b    = (const float*)d_in[6];
    const float* in_W    = (const float*)d_in[7];
    const float* conv_w  = (const float*)d_in[8];
    const float* conv_b  = (const float*)d_in[9];
    const float* xproj_W = (const float*)d_in[10];
    const float* dt_W    = (const float*)d_in[11];
    const float* dt_b    = (const float*)d_in[12];
    const float* A_log   = (const float*)d_in[13];
    const float* Dp      = (const float*)d_in[14];
    const float* out_W   = (const float*)d_in[15];
    const float* sl1_W   = (const float*)d_in[16];
    const float* sl1_b   = (const float*)d_in[17];
    const float* sl1_lnw = (const float*)d_in[18];
    const float* sl1_lnb = (const float*)d_in[19];
    const float* sl2_W   = (const float*)d_in[20];
    const float* sl2_b   = (const float*)d_in[21];
    const float* sl2_lnw = (const float*)d_in[22];
    const float* sl2_lnb = (const float*)d_in[23];
    const float* lat_lnw = (const float*)d_in[24];
    const float* lat_lnb = (const float*)d_in[25];
    float* out = (float*)d_out;
    float* ws  = (float*)d_ws;

    // ---- f32 workspace (floats) ----
    float* x      = ws + 0;          // 2,099,200
    u16*   xz_bf  = (u16*)(ws + 2099200);   // 4100*2048 u16 = 4,198,400 float-slots -> ends 6,297,600
    float* yh     = ws + 6297600;    // head: 2,099,200 -> ends 8,396,800
    float* t2     = ws + 8396800;    // head: 2,099,200 -> ends 10,496,000
    float* u      = ws + 10496000;   // 4,198,400 (head: a)
    float* xdbl   = ws + 14694400;   //   262,400 (head: pooled + softpool partials)
    float* scratch= ws + 14956800;   // 4,198,400 (patch tmp / xproj partials / head t1)
    // ---- bf16 pool ----
    u16* ub      = (u16*)(ws + 19155200);
    u16* regA    = ub + 0;          // img_bf / y_bf / yh_bf (4224x1024)
    u16* regB    = ub + 4325376;    // xn_bf / scan segbufs / x_bf (4224x512)
    u16* pWt     = ub + 6758400;
    u16* inWt    = ub + 7151616;
    u16* outWt   = ub + 9248768;
    u16* s1t     = ub + 10362880;
    u16* s2t     = ub + 10625024;

    float* a      = u;
    float* pooled = xdbl;
    float* spm    = xdbl + 8192;
    float* sps    = spm + 34816;
    float* spp    = sps + 34816;
    float* t1     = scratch;
    float* xprojP = scratch;
    float* segH   = (float*)regB;          // 524,288 floats
    float* segA   = segH + 524288;         // 458,752 floats

    // 0) prep
    prep_kernel<<<7040, 256, 0, stream>>>(img, patch_W, in_W, out_W, sl1_W, sl2_W,
                                          regA, pWt, inWt, outWt, s1t, s2t);

    // 1) patch GEMM + assemble
    gemm_mfma<2><<<dim3(512/128, 4096/64), 256, 0, stream>>>(
        regA, PDIM, pWt, scratch, DIM, 4096, DIM, PDIM, patch_b, nullptr, 0, nullptr);
    assemble_x<<<(MROWS*DIM)/256, 256, 0, stream>>>(scratch, cls_tok, pos_emb, x);

    // 2) mamba blocks
    for (int i = 0; i < NBLK; ++i) {
        ln_act<<<MROWS, 256, 0, stream>>>(x, ln_w + i*DIM, ln_b + i*DIM,
                                          nullptr, regB, 0);
        gemm_mfma<4><<<dim3(2048/128, 33), 256, 0, stream>>>(
            regB, DIM, inWt + (size_t)i*1048576, nullptr, 2048,
            MROWS, 2*DIN, DIM, nullptr, nullptr, 0, xz_bf);
        conv_silu<<<MROWS, 256, 0, stream>>>(
            xz_bf, conv_w + i*DIN*KCONV, conv_b + i*DIN, u);
        xproj_gemm<<<dim3(65, 4), 256, 0, stream>>>(
            u, xproj_W + (size_t)i*DIN*64, xprojP);
        xproj_reduce<<<1025, 256, 0, stream>>>(xprojP, xdbl);
        scan_phase1<<<dim3(64, 4, 7), 256, 0, stream>>>(
            u, xdbl, dt_W + (size_t)i*DTRANK*DIN, dt_b + i*DIN,
            A_log + (size_t)i*DIN*DSTATE, segA, segH);
        scan_mid<<<256, 256, 0, stream>>>(segH, segA);
        scan_phase2<<<dim3(64, 4, 8), 256, 0, stream>>>(
            u, xdbl, xz_bf, dt_W + (size_t)i*DTRANK*DIN, dt_b + i*DIN,
            A_log + (size_t)i*DIN*DSTATE, Dp + i*DIN, segH, regA);
        gemm_mfma<2><<<dim3(512/128, 65), 256, 0, stream>>>(
            regA, DIN, outWt + (size_t)i*524288, x, DIM,
            MROWS, DIM, DIN, nullptr, x, 0, (i == NBLK-1) ? regB : nullptr);
    }

    // 3) head
    gemm_mfma<2><<<dim3(512/128, 65), 256, 0, stream>>>(
        regB, DIM, s1t, t1, OUTD, MROWS, OUTD, DIM, sl1_b, nullptr, 0, nullptr);
    ln_act<<<MROWS, 256, 0, stream>>>(t1, sl1_lnw, sl1_lnb, yh, regA, 2);
    gemm_mfma<2><<<dim3(512/128, 65), 256, 0, stream>>>(
        regA, OUTD, s2t, t2, OUTD, MROWS, OUTD, OUTD, sl2_b, nullptr, 0, nullptr);
    ln_act<<<MROWS, 256, 0, stream>>>(t2, sl2_lnw, sl2_lnb, a, nullptr, 2);
    softpool_seg<<<dim3(OUTD/64, B_, NSEG_SP), 256, 0, stream>>>(a, yh, spm, sps, spp);
    softpool_combine<<<8, 256, 0, stream>>>(spm, sps, spp, pooled);
    ln_act<<<B_, 256, 0, stream>>>(pooled, lat_lnw, lat_lnb, out, nullptr, 0);
}